// Round 5
// baseline (113.568 us; speedup 1.0000x reference)
//
#include <hip/hip_runtime.h>
#include <hip/hip_bf16.h>
#include <math.h>

#define NROWS 4096
#define HD 512
#define HEADS 8
#define HDD 64
#define SEQ 1024
#define QSCALE 0.18033688011112042f   // 0.125 * log2(e)

typedef unsigned short u16;
typedef __attribute__((ext_vector_type(8))) short sh8;   // 8 bf16 (4 VGPRs)
typedef __attribute__((ext_vector_type(4))) float f4;    // MFMA accumulator

__device__ __forceinline__ f4 mfma16(sh8 a, sh8 b, f4 c) {
  return __builtin_amdgcn_mfma_f32_16x16x32_bf16(a, b, c, 0, 0, 0);
}

__device__ __forceinline__ u16 f2bf(float x) {
  union { float f; unsigned u; } v; v.f = x;
  unsigned r = v.u + 0x7fff + ((v.u >> 16) & 1);   // RNE
  return (u16)(r >> 16);
}

// XOR swizzles: spread same-column ds_read_b128 across 8 distinct 16B slots.
#define SWZA(r, cb) ((((r) * 128) + (cb)) ^ (((r) & 7) << 4))   // 128B rows
#define SWZB(r, cb) ((((r) * 256) + (cb)) ^ (((r) & 7) << 4))   // 256B rows

// ---------------- K1: p = LN(tanh(x @ Wp^T + bp)) ----------------
__global__ __launch_bounds__(256) void k_proj_ln(const float* __restrict__ x,
    const float* __restrict__ Wp, const float* __restrict__ bp,
    const float* __restrict__ g, const float* __restrict__ b,
    float* __restrict__ p) {
  int row  = blockIdx.x * 4 + (threadIdx.x >> 6);
  int lane = threadIdx.x & 63;
  const float* xr = x + row * HD + lane * 8;
  float4 xa = *(const float4*)xr;
  float4 xb = *(const float4*)(xr + 4);
  float acc[4];
#pragma unroll
  for (int j = 0; j < 4; ++j) {
    const float* wr = Wp + j * HD + lane * 8;
    float4 wa = *(const float4*)wr;
    float4 wb = *(const float4*)(wr + 4);
    acc[j] = xa.x*wa.x + xa.y*wa.y + xa.z*wa.z + xa.w*wa.w
           + xb.x*wb.x + xb.y*wb.y + xb.z*wb.z + xb.w*wb.w;
  }
#pragma unroll
  for (int j = 0; j < 4; ++j) {
#pragma unroll
    for (int off = 32; off >= 1; off >>= 1)
      acc[j] += __shfl_xor(acc[j], off);
  }
  if (lane == 0) {
    float v0 = tanhf(acc[0] + bp[0]);
    float v1 = tanhf(acc[1] + bp[1]);
    float v2 = tanhf(acc[2] + bp[2]);
    float v3 = tanhf(acc[3] + bp[3]);
    float mu = 0.25f * (v0 + v1 + v2 + v3);
    float d0 = v0 - mu, d1 = v1 - mu, d2 = v2 - mu, d3 = v3 - mu;
    float inv = rsqrtf(0.25f * (d0*d0 + d1*d1 + d2*d2 + d3*d3) + 1e-5f);
    *(float4*)(p + row * 4) = make_float4(d0*inv*g[0] + b[0], d1*inv*g[1] + b[1],
                                          d2*inv*g[2] + b[2], d3*inv*g[3] + b[3]);
  }
}

// ---------------- K2: table-driven prep: U (in LDS) then M[c][12][16][16] ----
// Small-code design: generic 2x2 gate loop (I$-friendly), state in LDS.
__global__ __launch_bounds__(256) void k_prep(
    const float* __restrict__ qw, const float* __restrict__ qe,
    const float* __restrict__ qg, const float* __restrict__ qb,
    const float* __restrict__ kw, const float* __restrict__ ke,
    const float* __restrict__ kg, const float* __restrict__ kb,
    const float* __restrict__ vw, const float* __restrict__ ve,
    const float* __restrict__ vg, const float* __restrict__ vb,
    float* __restrict__ Mout) {
  const int c = blockIdx.x;
  const int tid = threadIdx.x;
  __shared__ float aC[32], aS[32];
  __shared__ float GT[60][8];        // gate 2x2 complex: u00r,i,u01r,i,u10r,i,u11r,i
  __shared__ int   GM[60][2];        // mask, cmask
  __shared__ float PF[3][16][2];     // QAOA diagonal phase per (layer, amp)
  __shared__ float SR[16][17], SI[16][17];   // state [amp][col]
  __shared__ float TS[16], TI[16];
  __shared__ float Ur[256], Ui[256];

  const float* w = (c == 0) ? qw : (c == 1) ? kw : vw;
  const float* e = (c == 0) ? qe : (c == 1) ? ke : ve;
  const float* g = (c == 0) ? qg : (c == 1) ? kg : vg;
  const float* b = (c == 0) ? qb : (c == 1) ? kb : vb;

  // phase 0: half-angle sincos table
  if (tid < 30) {
    float ang = (tid < 12) ? w[tid] : (tid < 24) ? e[tid - 12]
               : (tid < 27) ? g[tid - 24] : b[tid - 27];
    float s_, c_;
    sincosf(0.5f * ang, &s_, &c_);
    aC[tid] = c_; aS[tid] = s_;
  }
  __syncthreads();

  // phase 1a: build 60-gate table (20 per layer)
  if (tid < 60) {
    int L = tid / 20, s5 = tid % 20;
    int typ, aidx, M, C;
    if (s5 < 12) {                       // RX/RY/RZ per qubit
      int q = s5 / 3; typ = s5 % 3; aidx = L * 4 + q; M = 8 >> q; C = 0;
    } else if (s5 < 16) {                // CRX ring
      int q = s5 - 12; typ = 0; aidx = 12 + L * 4 + q;
      C = 8 >> q; M = 8 >> ((q + 1) & 3);
    } else {                             // mixer RX
      int q = s5 - 16; typ = 0; aidx = 27 + L; M = 8 >> q; C = 0;
    }
    float cc = aC[aidx], ss = aS[aidx];
    float u0r = cc, u0i = 0.f, u1r = 0.f, u1i = 0.f,
          u2r = 0.f, u2i = 0.f, u3r = cc, u3i = 0.f;
    if (typ == 0)      { u1i = -ss; u2i = -ss; }            // RX
    else if (typ == 1) { u1r = -ss; u2r = ss; }             // RY
    else               { u0i = -ss; u3i = ss; }             // RZ
    GT[tid][0] = u0r; GT[tid][1] = u0i; GT[tid][2] = u1r; GT[tid][3] = u1i;
    GT[tid][4] = u2r; GT[tid][5] = u2i; GT[tid][6] = u3r; GT[tid][7] = u3i;
    GM[tid][0] = M; GM[tid][1] = C;
  }
  // phase 1b: QAOA diagonal phases (threads 64..111)
  if (tid >= 64 && tid < 112) {
    int idx = tid - 64, L = idx >> 4, a = idx & 15;
    float cg = aC[24 + L], sg = aS[24 + L];
    float c2 = cg * cg - sg * sg, s2 = 2.f * cg * sg;
    float c3 = cg * c2 - sg * s2, s3 = cg * s2 + sg * c2;
    int u = (a ^ (a >> 1)) & 7;
    int n = (u & 1) + ((u >> 1) & 1) + ((u >> 2) & 1);
    PF[L][a][0] = (n == 0 || n == 3) ? c3 : cg;
    PF[L][a][1] = (n == 0) ? -s3 : (n == 1) ? -sg : (n == 2) ? sg : s3;
  }
  // phase 1c: init state = identity columns
  for (int i = tid; i < 256; i += 256) {
    SR[i >> 4][i & 15] = (i >> 4) == (i & 15) ? 1.f : 0.f;
    SI[i >> 4][i & 15] = 0.f;
  }
  __syncthreads();

  // phase 2: run the circuit (128 active lanes = 8 pairs x 16 cols)
  const int p = tid >> 4, col = tid & 15;
  for (int L = 0; L < 3; ++L) {
    for (int s5 = 0; s5 < 16; ++s5) {       // rotations + CRX ring
      if (tid < 128) {
        int gi = L * 20 + s5;
        const float* u = GT[gi];
        int M = GM[gi][0], C = GM[gi][1];
        int lo = p & (M - 1);
        int a = ((p - lo) << 1) | lo;
        int bb = a | M;
        bool act = (C == 0) | ((a & C) != 0);
        float ar = SR[a][col], ai = SI[a][col];
        float br = SR[bb][col], bi = SI[bb][col];
        float nar = u[0]*ar - u[1]*ai + u[2]*br - u[3]*bi;
        float nai = u[0]*ai + u[1]*ar + u[2]*bi + u[3]*br;
        float nbr = u[4]*ar - u[5]*ai + u[6]*br - u[7]*bi;
        float nbi = u[4]*ai + u[5]*ar + u[6]*bi + u[7]*br;
        SR[a][col]  = act ? nar : ar;  SI[a][col]  = act ? nai : ai;
        SR[bb][col] = act ? nbr : br;  SI[bb][col] = act ? nbi : bi;
      }
      __syncthreads();
    }
    // diffusion: psi -= (sum psi)/8 per column
    if (tid < 16) {
      float sR = 0.f, sI = 0.f;
      for (int a = 0; a < 16; ++a) { sR += SR[a][tid]; sI += SI[a][tid]; }
      TS[tid] = sR * 0.125f; TI[tid] = sI * 0.125f;
    }
    __syncthreads();
    // subtract + QAOA phase (each lane owns amps 2p, 2p+1)
    if (tid < 128) {
      for (int k = 0; k < 2; ++k) {
        int a = 2 * p + k;
        float vr = SR[a][col] - TS[col];
        float vi = SI[a][col] - TI[col];
        float pc = PF[L][a][0], ps = PF[L][a][1];
        SR[a][col] = vr * pc - vi * ps;
        SI[a][col] = vr * ps + vi * pc;
      }
    }
    __syncthreads();
    for (int s5 = 16; s5 < 20; ++s5) {      // mixer RX
      if (tid < 128) {
        int gi = L * 20 + s5;
        const float* u = GT[gi];
        int M = GM[gi][0];
        int lo = p & (M - 1);
        int a = ((p - lo) << 1) | lo;
        int bb = a | M;
        float ar = SR[a][col], ai = SI[a][col];
        float br = SR[bb][col], bi = SI[bb][col];
        SR[a][col]  = u[0]*ar - u[1]*ai + u[2]*br - u[3]*bi;
        SI[a][col]  = u[0]*ai + u[1]*ar + u[2]*bi + u[3]*br;
        SR[bb][col] = u[4]*ar - u[5]*ai + u[6]*br - u[7]*bi;
        SI[bb][col] = u[4]*ai + u[5]*ar + u[6]*bi + u[7]*br;
      }
      __syncthreads();
    }
  }

  // phase 3: U -> dense LDS layout [k*16+col]
  for (int i = tid; i < 256; i += 256) {
    Ur[i] = SR[i >> 4][i & 15];
    Ui[i] = SI[i >> 4][i & 15];
  }
  __syncthreads();

  // phase 4: M[j][a][b] = Re( sum_k conj(U[k][a]) (P_j U)[k][b] )
  if (tid < 192) {
    const int j = tid >> 4, a = tid & 15;
    const int typ = j >> 2;               // 0=Z 1=X 2=Y
    const int Mm = 8 >> (j & 3);
    float ax[4] = {0.f,0.f,0.f,0.f}, ay[4] = {0.f,0.f,0.f,0.f},
          az[4] = {0.f,0.f,0.f,0.f}, aw[4] = {0.f,0.f,0.f,0.f};
#pragma clang loop unroll_count(4)
    for (int k = 0; k < 16; ++k) {
      float uar = Ur[k * 16 + a], uai = Ui[k * 16 + a];
      int k2; float cR, cI;
      if (typ == 0)      { k2 = k;      float z = (k & Mm) ? -1.f : 1.f; cR = z*uar; cI = z*uai; }
      else if (typ == 1) { k2 = k ^ Mm; cR = uar; cI = uai; }
      else               { k2 = k ^ Mm; float sg = (k & Mm) ? 1.f : -1.f; cR = sg*uai; cI = -sg*uar; }
      const float* ur2 = Ur + k2 * 16;
      const float* ui2 = Ui + k2 * 16;
#pragma unroll
      for (int i = 0; i < 4; ++i) {
        ax[i] += cR * ur2[i*4+0] + cI * ui2[i*4+0];
        ay[i] += cR * ur2[i*4+1] + cI * ui2[i*4+1];
        az[i] += cR * ur2[i*4+2] + cI * ui2[i*4+2];
        aw[i] += cR * ur2[i*4+3] + cI * ui2[i*4+3];
      }
    }
    float* dst = Mout + ((c * 12 + j) * 16 + a) * 16;
#pragma unroll
    for (int i = 0; i < 4; ++i)
      ((float4*)dst)[i] = make_float4(ax[i], ay[i], az[i], aw[i]);
  }
}

// ---------------- K2c: t[c][row][12] via quadratic forms ----------------
__global__ __launch_bounds__(64) void k_tvals(const float* __restrict__ p,
    const float* __restrict__ Mg, float* __restrict__ t) {
  const int c = blockIdx.x % 3, rb = blockIdx.x / 3;
  const int tid = threadIdx.x;
  const int row = rb * 64 + tid;
  __shared__ float Ml[3072];
  const float4* src = (const float4*)(Mg + c * 3072);
#pragma unroll
  for (int i = 0; i < 12; ++i)
    ((float4*)Ml)[tid + i * 64] = src[tid + i * 64];
  __syncthreads();

  float4 in4 = *(const float4*)(p + row * 4);
  float cs[4], sn[4];
  sincosf(0.5f * in4.x, &sn[0], &cs[0]);
  sincosf(0.5f * in4.y, &sn[1], &cs[1]);
  sincosf(0.5f * in4.z, &sn[2], &cs[2]);
  sincosf(0.5f * in4.w, &sn[3], &cs[3]);
  float q01[4] = {cs[0]*cs[1], cs[0]*sn[1], sn[0]*cs[1], sn[0]*sn[1]};
  float q23[4] = {cs[2]*cs[3], cs[2]*sn[3], sn[2]*cs[3], sn[2]*sn[3]};
  float psi[16];
#pragma unroll
  for (int a = 0; a < 16; ++a) psi[a] = q01[a >> 2] * q23[a & 3];

  float* to = t + (c * NROWS + row) * 12;
#pragma clang loop unroll(disable)
  for (int j = 0; j < 12; ++j) {
    const float* Mj = Ml + j * 256;
    float y = 0.f;
#pragma unroll
    for (int a = 0; a < 16; ++a) {
      const float4* mr = (const float4*)(Mj + a * 16);
      float rsum = 0.f;
#pragma unroll
      for (int i = 0; i < 4; ++i) {
        float4 m4 = mr[i];
        rsum += m4.x*psi[i*4] + m4.y*psi[i*4+1] + m4.z*psi[i*4+2] + m4.w*psi[i*4+3];
      }
      y += psi[a] * rsum;
    }
    to[j] = y;
  }
}

// -------- K3: q/k/v = t @ W^T + b -> bf16; Q scaled; V transposed [bh][64][s]
__global__ __launch_bounds__(256) void k_qkvproj(const float* __restrict__ t,
    const float* __restrict__ Wq, const float* __restrict__ bq,
    const float* __restrict__ Wk, const float* __restrict__ bk,
    const float* __restrict__ Wv, const float* __restrict__ bv,
    u16* __restrict__ Qo, u16* __restrict__ Ko, u16* __restrict__ Vto) {
  int n = blockIdx.x;
  int tid = threadIdx.x;
  __shared__ float tt[3][12];
  if (tid < 36) {
    int cc = tid / 12, j = tid - cc * 12;
    tt[cc][j] = t[(cc * NROWS + n) * 12 + j];
  }
  __syncthreads();
  int bb = n >> 10, ss = n & 1023;
  for (int o = tid; o < HD; o += 256) {
    int h = o >> 6, d = o & 63;
    float aq = bq[o], ak = bk[o], av = bv[o];
#pragma unroll
    for (int j = 0; j < 12; ++j) {
      aq += tt[0][j] * Wq[o * 12 + j];
      ak += tt[1][j] * Wk[o * 12 + j];
      av += tt[2][j] * Wv[o * 12 + j];
    }
    int bhh = bb * HEADS + h;
    Qo[(bhh * SEQ + ss) * HDD + d] = f2bf(aq * QSCALE);
    Ko[(bhh * SEQ + ss) * HDD + d] = f2bf(ak);
    Vto[(bhh * HDD + d) * SEQ + ss] = f2bf(av);
  }
}

// ---------------- K4: MFMA flash attention, max-free softmax ----------------
// grid (16 qtiles, 32 bh); 4 waves; wave owns 16 q-rows; KV chunk 128.
__global__ __launch_bounds__(256) void k_attn_mfma(const u16* __restrict__ Q,
    const u16* __restrict__ K, const u16* __restrict__ Vt,
    u16* __restrict__ Ob) {
  const int bh = blockIdx.y, qt = blockIdx.x;
  const int tid = threadIdx.x, w = tid >> 6, l = tid & 63;
  const int lr = l & 15, lh = l >> 4;

  __shared__ u16 Kl[128 * 64];       // [key][d]   swizzled, 128B rows
  __shared__ u16 Vl[64 * 128];       // [d][key]   swizzled, 256B rows
  __shared__ u16 Pl[4][16 * 128];    // per-wave [q][key] swizzled, 256B rows

  const u16* Qb = Q + (bh * SEQ + qt * 64) * HDD;
  const u16* Kb = K + bh * SEQ * HDD;
  const u16* Vb = Vt + bh * HDD * SEQ;

  sh8 qf[2];
#pragma unroll
  for (int kk = 0; kk < 2; ++kk)
    qf[kk] = *(const sh8*)(Qb + (w * 16 + lr) * HDD + kk * 32 + lh * 8);

  f4 oacc[4];
  float lsum[4] = {0.f, 0.f, 0.f, 0.f};
#pragma unroll
  for (int n = 0; n < 4; ++n) oacc[n] = (f4){0.f, 0.f, 0.f, 0.f};

  for (int ch = 0; ch < SEQ / 128; ++ch) {
    __syncthreads();                       // prev chunk fully consumed
#pragma unroll
    for (int i = 0; i < 4; ++i) {          // stage K 128x64
      int idx = i * 256 + tid;
      int r = idx >> 3, c8 = idx & 7;
      *(sh8*)((char*)Kl + SWZA(r, c8 * 16)) =
          *(const sh8*)(Kb + (ch * 128 + r) * HDD + c8 * 8);
    }
#pragma unroll
    for (int i = 0; i < 4; ++i) {          // stage V^T 64x128
      int idx = i * 256 + tid;
      int r = idx >> 4, c8 = idx & 15;
      *(sh8*)((char*)Vl + SWZB(r, c8 * 16)) =
          *(const sh8*)(Vb + r * SEQ + ch * 128 + c8 * 8);
    }
    __syncthreads();

    // S = Q K^T  (Q pre-scaled so S is already in log2 units)
    f4 sacc[8];
#pragma unroll
    for (int n = 0; n < 8; ++n) sacc[n] = (f4){0.f, 0.f, 0.f, 0.f};
#pragma unroll
    for (int kk = 0; kk < 2; ++kk) {
#pragma unroll
      for (int n = 0; n < 8; ++n) {
        sh8 kf = *(const sh8*)((const char*)Kl + SWZA(n * 16 + lr, kk * 64 + lh * 16));
        sacc[n] = mfma16(qf[kk], kf, sacc[n]);
      }
    }

    // P = 2^S, accumulate row partial sums, write P to per-wave LDS
#pragma unroll
    for (int n = 0; n < 8; ++n) {
#pragma unroll
      for (int r = 0; r < 4; ++r) {
        float pv = exp2f(sacc[n][r]);
        lsum[r] += pv;
        *(u16*)((char*)Pl[w] + SWZB(lh * 4 + r, (n * 16 + lr) * 2)) = f2bf(pv);
      }
    }
    // no barrier needed: Pl is per-wave, lgkmcnt ordering suffices

    // O += P V
#pragma unroll
    for (int kk = 0; kk < 4; ++kk) {
      sh8 pf = *(const sh8*)((const char*)Pl[w] + SWZB(lr, kk * 64 + lh * 16));
#pragma unroll
      for (int n = 0; n < 4; ++n) {
        sh8 vf = *(const sh8*)((const char*)Vl + SWZB(n * 16 + lr, kk * 64 + lh * 16));
        oacc[n] = mfma16(pf, vf, oacc[n]);
      }
    }
  }

  // final row-sum reduce across the 16-lane lr group (once per kernel)
#pragma unroll
  for (int r = 0; r < 4; ++r) {
    lsum[r] += __shfl_xor(lsum[r], 1); lsum[r] += __shfl_xor(lsum[r], 2);
    lsum[r] += __shfl_xor(lsum[r], 4); lsum[r] += __shfl_xor(lsum[r], 8);
  }

  int bb = bh >> 3, h = bh & 7;
#pragma unroll
  for (int r = 0; r < 4; ++r) {
    int row = qt * 64 + w * 16 + lh * 4 + r;
    float inv = 1.f / lsum[r];
#pragma unroll
    for (int n = 0; n < 4; ++n)
      Ob[(bb * SEQ + row) * HD + h * 64 + n * 16 + lr] = f2bf(oacc[n][r] * inv);
  }
}

// ---------------- K5: out = a @ Wo^T + bo (MFMA) ----------------
__global__ __launch_bounds__(256) void k_oproj_mfma(const u16* __restrict__ A,
    const u16* __restrict__ W, const float* __restrict__ bo,
    float* __restrict__ out) {
  const int nb = blockIdx.x, ob = blockIdx.y;
  const int tid = threadIdx.x, w = tid >> 6, l = tid & 63;
  const int lr = l & 15, lh = l >> 4;
  __shared__ u16 Al[64 * 64];
  __shared__ u16 Wl[64 * 64];
  f4 acc[4];
#pragma unroll
  for (int n = 0; n < 4; ++n) acc[n] = (f4){0.f, 0.f, 0.f, 0.f};
  for (int ch = 0; ch < 8; ++ch) {
    __syncthreads();
#pragma unroll
    for (int i = 0; i < 2; ++i) {
      int idx = i * 256 + tid;
      int r = idx >> 3, c8 = idx & 7;
      *(sh8*)((char*)Al + SWZA(r, c8 * 16)) =
          *(const sh8*)(A + (nb * 64 + r) * HD + ch * 64 + c8 * 8);
      *(sh8*)((char*)Wl + SWZA(r, c8 * 16)) =
          *(const sh8*)(W + (ob * 64 + r) * HD + ch * 64 + c8 * 8);
    }
    __syncthreads();
#pragma unroll
    for (int kk = 0; kk < 2; ++kk) {
      sh8 af = *(const sh8*)((const char*)Al + SWZA(w * 16 + lr, kk * 64 + lh * 16));
#pragma unroll
      for (int n = 0; n < 4; ++n) {
        sh8 wf = *(const sh8*)((const char*)Wl + SWZA(n * 16 + lr, kk * 64 + lh * 16));
        acc[n] = mfma16(af, wf, acc[n]);
      }
    }
  }
#pragma unroll
  for (int r = 0; r < 4; ++r) {
    int row = nb * 64 + w * 16 + lh * 4 + r;
#pragma unroll
    for (int n = 0; n < 4; ++n) {
      int col = ob * 64 + n * 16 + lr;
      out[row * HD + col] = acc[n][r] + bo[col];
    }
  }
}

// ---------------- K6: fp32 -> bf16 convert (Wo) ----------------
__global__ __launch_bounds__(256) void k_cvt(const float* __restrict__ in,
                                             u16* __restrict__ o, int n) {
  int i = (blockIdx.x * 256 + threadIdx.x) * 4;
  if (i < n) {
    float4 v = *(const float4*)(in + i);
    o[i]   = f2bf(v.x); o[i+1] = f2bf(v.y);
    o[i+2] = f2bf(v.z); o[i+3] = f2bf(v.w);
  }
}

// ---------------- launch ----------------
extern "C" void kernel_launch(void* const* d_in, const int* in_sizes, int n_in,
                              void* d_out, int out_size, void* d_ws, size_t ws_size,
                              hipStream_t stream) {
  const float* x    = (const float*)d_in[0];
  const float* Wp   = (const float*)d_in[1];
  const float* bp   = (const float*)d_in[2];
  const float* ln_g = (const float*)d_in[3];
  const float* ln_b = (const float*)d_in[4];
  const float* qw   = (const float*)d_in[5];
  const float* qe   = (const float*)d_in[6];
  const float* qg   = (const float*)d_in[7];
  const float* qb_  = (const float*)d_in[8];
  const float* kw   = (const float*)d_in[9];
  const float* ke   = (const float*)d_in[10];
  const float* kg   = (const float*)d_in[11];
  const float* kb_  = (const float*)d_in[12];
  const float* vw   = (const float*)d_in[13];
  const float* ve   = (const float*)d_in[14];
  const float* vg   = (const float*)d_in[15];
  const float* vb_  = (const float*)d_in[16];
  const float* Wq   = (const float*)d_in[17];
  const float* bq   = (const float*)d_in[18];
  const float* Wk   = (const float*)d_in[19];
  const float* bk   = (const float*)d_in[20];
  const float* Wv   = (const float*)d_in[21];
  const float* bv   = (const float*)d_in[22];
  const float* Wo   = (const float*)d_in[23];
  const float* bo   = (const float*)d_in[24];

  float* ws   = (float*)d_ws;
  float* pbuf = ws;                        // 16384 f
  float* tbuf = ws + 16384;                // 147456 f
  float* Mbuf = tbuf + 147456;             // 9216 f
  u16* qb  = (u16*)(Mbuf + 9216 + 1536);   // 32*1024*64  (layout as round 4)
  u16* kb  = qb + 32 * SEQ * HDD;
  u16* vtb = kb + 32 * SEQ * HDD;
  u16* ab  = vtb + 32 * SEQ * HDD;         // 4096*512
  u16* wob = ab + NROWS * HD;              // 512*512

  k_prep<<<3, 256, 0, stream>>>(qw, qe, qg, qb_, kw, ke, kg, kb_,
                                vw, ve, vg, vb_, Mbuf);
  k_proj_ln<<<NROWS / 4, 256, 0, stream>>>(x, Wp, bp, ln_g, ln_b, pbuf);
  k_tvals<<<192, 64, 0, stream>>>(pbuf, Mbuf, tbuf);
  k_qkvproj<<<NROWS, 256, 0, stream>>>(tbuf, Wq, bq, Wk, bk, Wv, bv,
                                       qb, kb, vtb);
  k_cvt<<<(HD * HD) / 1024, 256, 0, stream>>>(Wo, wob, HD * HD);
  dim3 ga(SEQ / 64, 32);
  k_attn_mfma<<<ga, 256, 0, stream>>>(qb, kb, vtb, ab);
  dim3 go(NROWS / 64, HD / 64);
  k_oproj_mfma<<<go, 256, 0, stream>>>(ab, wob, bo, (float*)d_out);
}

// Round 6
// 86.423 us; speedup vs baseline: 1.3141x; 1.3141x over previous
//
#include <hip/hip_runtime.h>
#include <hip/hip_bf16.h>
#include <math.h>

#define NROWS 4096
#define HD 512
#define HEADS 8
#define HDD 64
#define SEQ 1024
#define QSCALE 0.18033688011112042f   // 0.125 * log2(e)

typedef unsigned short u16;
typedef __attribute__((ext_vector_type(8))) short sh8;   // 8 bf16 (4 VGPRs)
typedef __attribute__((ext_vector_type(4))) float f4;    // MFMA accumulator

__device__ __forceinline__ f4 mfma16(sh8 a, sh8 b, f4 c) {
  return __builtin_amdgcn_mfma_f32_16x16x32_bf16(a, b, c, 0, 0, 0);
}

__device__ __forceinline__ u16 f2bf(float x) {
  union { float f; unsigned u; } v; v.f = x;
  unsigned r = v.u + 0x7fff + ((v.u >> 16) & 1);   // RNE
  return (u16)(r >> 16);
}

// XOR swizzles: spread same-column ds_read_b128 across 8 distinct 16B slots.
#define SWZA(r, cb) ((((r) * 128) + (cb)) ^ (((r) & 7) << 4))   // 128B rows
#define SWZB(r, cb) ((((r) * 256) + (cb)) ^ (((r) & 7) << 4))   // 256B rows

// ---------------- K0: table-driven prep: U (in LDS) then M[c][12][16][16] ----
__global__ __launch_bounds__(256) void k_prep(
    const float* __restrict__ qw, const float* __restrict__ qe,
    const float* __restrict__ qg, const float* __restrict__ qb,
    const float* __restrict__ kw, const float* __restrict__ ke,
    const float* __restrict__ kg, const float* __restrict__ kb,
    const float* __restrict__ vw, const float* __restrict__ ve,
    const float* __restrict__ vg, const float* __restrict__ vb,
    float* __restrict__ Mout) {
  const int c = blockIdx.x;
  const int tid = threadIdx.x;
  __shared__ float aC[32], aS[32];
  __shared__ float GT[60][8];
  __shared__ int   GM[60][2];
  __shared__ float PF[3][16][2];
  __shared__ float SR[16][17], SI[16][17];
  __shared__ float TS[16], TI[16];
  __shared__ float Ur[256], Ui[256];

  const float* w = (c == 0) ? qw : (c == 1) ? kw : vw;
  const float* e = (c == 0) ? qe : (c == 1) ? ke : ve;
  const float* g = (c == 0) ? qg : (c == 1) ? kg : vg;
  const float* b = (c == 0) ? qb : (c == 1) ? kb : vb;

  if (tid < 30) {
    float ang = (tid < 12) ? w[tid] : (tid < 24) ? e[tid - 12]
               : (tid < 27) ? g[tid - 24] : b[tid - 27];
    float s_, c_;
    sincosf(0.5f * ang, &s_, &c_);
    aC[tid] = c_; aS[tid] = s_;
  }
  __syncthreads();

  if (tid < 60) {
    int L = tid / 20, s5 = tid % 20;
    int typ, aidx, M, C;
    if (s5 < 12) {
      int q = s5 / 3; typ = s5 % 3; aidx = L * 4 + q; M = 8 >> q; C = 0;
    } else if (s5 < 16) {
      int q = s5 - 12; typ = 0; aidx = 12 + L * 4 + q;
      C = 8 >> q; M = 8 >> ((q + 1) & 3);
    } else {
      int q = s5 - 16; typ = 0; aidx = 27 + L; M = 8 >> q; C = 0;
    }
    float cc = aC[aidx], ss = aS[aidx];
    float u0r = cc, u0i = 0.f, u1r = 0.f, u1i = 0.f,
          u2r = 0.f, u2i = 0.f, u3r = cc, u3i = 0.f;
    if (typ == 0)      { u1i = -ss; u2i = -ss; }
    else if (typ == 1) { u1r = -ss; u2r = ss; }
    else               { u0i = -ss; u3i = ss; }
    GT[tid][0] = u0r; GT[tid][1] = u0i; GT[tid][2] = u1r; GT[tid][3] = u1i;
    GT[tid][4] = u2r; GT[tid][5] = u2i; GT[tid][6] = u3r; GT[tid][7] = u3i;
    GM[tid][0] = M; GM[tid][1] = C;
  }
  if (tid >= 64 && tid < 112) {
    int idx = tid - 64, L = idx >> 4, a = idx & 15;
    float cg = aC[24 + L], sg = aS[24 + L];
    float c2 = cg * cg - sg * sg, s2 = 2.f * cg * sg;
    float c3 = cg * c2 - sg * s2, s3 = cg * s2 + sg * c2;
    int u = (a ^ (a >> 1)) & 7;
    int n = (u & 1) + ((u >> 1) & 1) + ((u >> 2) & 1);
    PF[L][a][0] = (n == 0 || n == 3) ? c3 : cg;
    PF[L][a][1] = (n == 0) ? -s3 : (n == 1) ? -sg : (n == 2) ? sg : s3;
  }
  for (int i = tid; i < 256; i += 256) {
    SR[i >> 4][i & 15] = (i >> 4) == (i & 15) ? 1.f : 0.f;
    SI[i >> 4][i & 15] = 0.f;
  }
  __syncthreads();

  const int p = tid >> 4, col = tid & 15;
  for (int L = 0; L < 3; ++L) {
    for (int s5 = 0; s5 < 16; ++s5) {
      if (tid < 128) {
        int gi = L * 20 + s5;
        const float* u = GT[gi];
        int M = GM[gi][0], C = GM[gi][1];
        int lo = p & (M - 1);
        int a = ((p - lo) << 1) | lo;
        int bb = a | M;
        bool act = (C == 0) | ((a & C) != 0);
        float ar = SR[a][col], ai = SI[a][col];
        float br = SR[bb][col], bi = SI[bb][col];
        float nar = u[0]*ar - u[1]*ai + u[2]*br - u[3]*bi;
        float nai = u[0]*ai + u[1]*ar + u[2]*bi + u[3]*br;
        float nbr = u[4]*ar - u[5]*ai + u[6]*br - u[7]*bi;
        float nbi = u[4]*ai + u[5]*ar + u[6]*bi + u[7]*br;
        SR[a][col]  = act ? nar : ar;  SI[a][col]  = act ? nai : ai;
        SR[bb][col] = act ? nbr : br;  SI[bb][col] = act ? nbi : bi;
      }
      __syncthreads();
    }
    if (tid < 16) {
      float sR = 0.f, sI = 0.f;
      for (int a = 0; a < 16; ++a) { sR += SR[a][tid]; sI += SI[a][tid]; }
      TS[tid] = sR * 0.125f; TI[tid] = sI * 0.125f;
    }
    __syncthreads();
    if (tid < 128) {
      for (int k = 0; k < 2; ++k) {
        int a = 2 * p + k;
        float vr = SR[a][col] - TS[col];
        float vi = SI[a][col] - TI[col];
        float pc = PF[L][a][0], ps = PF[L][a][1];
        SR[a][col] = vr * pc - vi * ps;
        SI[a][col] = vr * ps + vi * pc;
      }
    }
    __syncthreads();
    for (int s5 = 16; s5 < 20; ++s5) {
      if (tid < 128) {
        int gi = L * 20 + s5;
        const float* u = GT[gi];
        int M = GM[gi][0];
        int lo = p & (M - 1);
        int a = ((p - lo) << 1) | lo;
        int bb = a | M;
        float ar = SR[a][col], ai = SI[a][col];
        float br = SR[bb][col], bi = SI[bb][col];
        SR[a][col]  = u[0]*ar - u[1]*ai + u[2]*br - u[3]*bi;
        SI[a][col]  = u[0]*ai + u[1]*ar + u[2]*bi + u[3]*br;
        SR[bb][col] = u[4]*ar - u[5]*ai + u[6]*br - u[7]*bi;
        SI[bb][col] = u[4]*ai + u[5]*ar + u[6]*bi + u[7]*br;
      }
      __syncthreads();
    }
  }

  for (int i = tid; i < 256; i += 256) {
    Ur[i] = SR[i >> 4][i & 15];
    Ui[i] = SI[i >> 4][i & 15];
  }
  __syncthreads();

  if (tid < 192) {
    const int j = tid >> 4, a = tid & 15;
    const int typ = j >> 2;
    const int Mm = 8 >> (j & 3);
    float ax[4] = {0.f,0.f,0.f,0.f}, ay[4] = {0.f,0.f,0.f,0.f},
          az[4] = {0.f,0.f,0.f,0.f}, aw[4] = {0.f,0.f,0.f,0.f};
#pragma clang loop unroll_count(4)
    for (int k = 0; k < 16; ++k) {
      float uar = Ur[k * 16 + a], uai = Ui[k * 16 + a];
      int k2; float cR, cI;
      if (typ == 0)      { k2 = k;      float z = (k & Mm) ? -1.f : 1.f; cR = z*uar; cI = z*uai; }
      else if (typ == 1) { k2 = k ^ Mm; cR = uar; cI = uai; }
      else               { k2 = k ^ Mm; float sg = (k & Mm) ? 1.f : -1.f; cR = sg*uai; cI = -sg*uar; }
      const float* ur2 = Ur + k2 * 16;
      const float* ui2 = Ui + k2 * 16;
#pragma unroll
      for (int i = 0; i < 4; ++i) {
        ax[i] += cR * ur2[i*4+0] + cI * ui2[i*4+0];
        ay[i] += cR * ur2[i*4+1] + cI * ui2[i*4+1];
        az[i] += cR * ur2[i*4+2] + cI * ui2[i*4+2];
        aw[i] += cR * ur2[i*4+3] + cI * ui2[i*4+3];
      }
    }
    float* dst = Mout + ((c * 12 + j) * 16 + a) * 16;
#pragma unroll
    for (int i = 0; i < 4; ++i)
      ((float4*)dst)[i] = make_float4(ax[i], ay[i], az[i], aw[i]);
  }
}

// ---- K1 fused: x -> p (LN(tanh)) -> psi -> t (quad forms) -> q/k/v bf16 ----
// grid 256 blocks x 16 rows; Q,K row-major [bh][s][64]; V transposed [bh][64][s]
__global__ __launch_bounds__(256) void k_fused(const float* __restrict__ x,
    const float* __restrict__ Wp, const float* __restrict__ bp,
    const float* __restrict__ ln_g, const float* __restrict__ ln_b,
    const float* __restrict__ Mg,
    const float* __restrict__ Wq, const float* __restrict__ bq,
    const float* __restrict__ Wk, const float* __restrict__ bk,
    const float* __restrict__ Wv, const float* __restrict__ bv,
    u16* __restrict__ Qo, u16* __restrict__ Ko, u16* __restrict__ Vto) {
  const int rb = blockIdx.x;
  const int tid = threadIdx.x;
  __shared__ float Ml[3][12][256];     // 36 KB
  __shared__ float pl[16][4];
  __shared__ float psil[16][17];
  __shared__ float tt[3][16][12];

  { // stage M (broadcast from L2)
    const float4* src = (const float4*)Mg;
    float4* dst = (float4*)&Ml[0][0][0];
    for (int i = tid; i < 2304; i += 256) dst[i] = src[i];
  }

  // ---- phase A: p = LN(tanh(x @ Wp^T + bp)) for 16 rows ----
  const int w = tid >> 6, lane = tid & 63;
  {
    float4 wpa[4], wpb[4];
#pragma unroll
    for (int j = 0; j < 4; ++j) {
      wpa[j] = *(const float4*)(Wp + j * HD + lane * 8);
      wpb[j] = *(const float4*)(Wp + j * HD + lane * 8 + 4);
    }
    for (int i = 0; i < 4; ++i) {
      int r = w * 4 + i;
      const float* xr = x + (rb * 16 + r) * HD + lane * 8;
      float4 xa = *(const float4*)xr, xb = *(const float4*)(xr + 4);
      float acc[4];
#pragma unroll
      for (int j = 0; j < 4; ++j)
        acc[j] = xa.x*wpa[j].x + xa.y*wpa[j].y + xa.z*wpa[j].z + xa.w*wpa[j].w
               + xb.x*wpb[j].x + xb.y*wpb[j].y + xb.z*wpb[j].z + xb.w*wpb[j].w;
#pragma unroll
      for (int j = 0; j < 4; ++j)
#pragma unroll
        for (int off = 32; off >= 1; off >>= 1)
          acc[j] += __shfl_xor(acc[j], off);
      if (lane == 0) {
        float v0 = tanhf(acc[0] + bp[0]);
        float v1 = tanhf(acc[1] + bp[1]);
        float v2 = tanhf(acc[2] + bp[2]);
        float v3 = tanhf(acc[3] + bp[3]);
        float mu = 0.25f * (v0 + v1 + v2 + v3);
        float d0 = v0 - mu, d1 = v1 - mu, d2 = v2 - mu, d3 = v3 - mu;
        float inv = rsqrtf(0.25f * (d0*d0 + d1*d1 + d2*d2 + d3*d3) + 1e-5f);
        pl[r][0] = d0 * inv * ln_g[0] + ln_b[0];
        pl[r][1] = d1 * inv * ln_g[1] + ln_b[1];
        pl[r][2] = d2 * inv * ln_g[2] + ln_b[2];
        pl[r][3] = d3 * inv * ln_g[3] + ln_b[3];
      }
    }
  }
  __syncthreads();

  // ---- phase B1: psi per row ----
  if (tid < 16) {
    float cs[4], sn[4];
    sincosf(0.5f * pl[tid][0], &sn[0], &cs[0]);
    sincosf(0.5f * pl[tid][1], &sn[1], &cs[1]);
    sincosf(0.5f * pl[tid][2], &sn[2], &cs[2]);
    sincosf(0.5f * pl[tid][3], &sn[3], &cs[3]);
    float q01[4] = {cs[0]*cs[1], cs[0]*sn[1], sn[0]*cs[1], sn[0]*sn[1]};
    float q23[4] = {cs[2]*cs[3], cs[2]*sn[3], sn[2]*cs[3], sn[2]*sn[3]};
#pragma unroll
    for (int a = 0; a < 16; ++a) psil[tid][a] = q01[a >> 2] * q23[a & 3];
  }
  __syncthreads();

  // ---- phase B2: t[c][r][j] = psi^T M psi ----
  if (tid < 192) {
    const int r = tid & 15, j = tid >> 4;
    float psi[16];
#pragma unroll
    for (int a = 0; a < 16; ++a) psi[a] = psil[r][a];
#pragma clang loop unroll(disable)
    for (int c = 0; c < 3; ++c) {
      const float* Mj = &Ml[c][j][0];
      float y = 0.f;
#pragma unroll
      for (int a = 0; a < 16; ++a) {
        float rsum = 0.f;
#pragma unroll
        for (int i = 0; i < 16; ++i) rsum += Mj[a*16+i] * psi[i];
        y += psi[a] * rsum;
      }
      tt[c][r][j] = y;
    }
  }
  __syncthreads();

  // ---- phase C: QKV projection, coalesced bf16 writes ----
  const int n0 = rb * 16, b = n0 >> 10, ss0 = n0 & 1023;
  { // Q and K: thread owns output col pair (2t, 2t+1)
    const int o0 = tid * 2;
    float wq0[12], wq1[12], wk0[12], wk1[12];
#pragma unroll
    for (int j = 0; j < 12; ++j) {
      wq0[j] = Wq[o0*12 + j];  wq1[j] = Wq[(o0+1)*12 + j];
      wk0[j] = Wk[o0*12 + j];  wk1[j] = Wk[(o0+1)*12 + j];
    }
    const float bq0 = bq[o0], bq1 = bq[o0+1], bk0 = bk[o0], bk1 = bk[o0+1];
    const int h = o0 >> 6, d = o0 & 63;
    u16* qrow = Qo + ((b * HEADS + h) * SEQ + ss0) * HDD + d;
    u16* krow = Ko + ((b * HEADS + h) * SEQ + ss0) * HDD + d;
    for (int rr = 0; rr < 16; ++rr) {
      float a0 = bq0, a1 = bq1, c0 = bk0, c1 = bk1;
#pragma unroll
      for (int j = 0; j < 12; ++j) {
        float tq = tt[0][rr][j], tk = tt[1][rr][j];
        a0 += tq * wq0[j]; a1 += tq * wq1[j];
        c0 += tk * wk0[j]; c1 += tk * wk1[j];
      }
      unsigned qv = (unsigned)f2bf(a0 * QSCALE) | ((unsigned)f2bf(a1 * QSCALE) << 16);
      unsigned kv = (unsigned)f2bf(c0) | ((unsigned)f2bf(c1) << 16);
      *(unsigned*)(qrow + rr * HDD) = qv;
      *(unsigned*)(krow + rr * HDD) = kv;
    }
  }
  { // V^T: thread owns (row-pair, o-stripe); 32B contiguous runs per 8 threads
    const int sp = tid & 7, gg = tid >> 3;
    const int r0 = 2 * sp, r1 = r0 + 1;
    for (int i = 0; i < 16; ++i) {
      int o = gg + 32 * i;
      float v0 = bv[o], v1 = bv[o];
#pragma unroll
      for (int j = 0; j < 12; ++j) {
        float wv = Wv[o * 12 + j];
        v0 += tt[2][r0][j] * wv;
        v1 += tt[2][r1][j] * wv;
      }
      unsigned vv = (unsigned)f2bf(v0) | ((unsigned)f2bf(v1) << 16);
      *(unsigned*)(Vto + (b * 512 + o) * SEQ + ss0 + r0) = vv;
    }
  }
}

// ---------------- K2: MFMA flash attention, reg-staged double buffer ----------
__global__ __launch_bounds__(256) void k_attn_mfma(const u16* __restrict__ Q,
    const u16* __restrict__ K, const u16* __restrict__ Vt,
    u16* __restrict__ Ob) {
  const int bh = blockIdx.y, qt = blockIdx.x;
  const int tid = threadIdx.x, w = tid >> 6, l = tid & 63;
  const int lr = l & 15, lh = l >> 4;

  __shared__ u16 Kl[2][128 * 64];    // [key][d]  swizzled, 128B rows
  __shared__ u16 Vl[2][64 * 128];    // [d][key]  swizzled, 256B rows
  __shared__ u16 Pl[4][16 * 128];    // per-wave [q][key] swizzled

  const u16* Qb = Q + (bh * SEQ + qt * 64) * HDD;
  const u16* Kb = K + bh * SEQ * HDD;
  const u16* Vb = Vt + bh * HDD * SEQ;

  sh8 qf[2];
#pragma unroll
  for (int kk = 0; kk < 2; ++kk)
    qf[kk] = *(const sh8*)(Qb + (w * 16 + lr) * HDD + kk * 32 + lh * 8);

  f4 oacc[4];
  float lsum[4] = {0.f, 0.f, 0.f, 0.f};
#pragma unroll
  for (int n = 0; n < 4; ++n) oacc[n] = (f4){0.f, 0.f, 0.f, 0.f};

  sh8 kreg[4], vreg[4];

#define STAGE_LOAD(ch) { \
    _Pragma("unroll") \
    for (int i = 0; i < 4; ++i) { \
      int idx = i * 256 + tid; \
      kreg[i] = *(const sh8*)(Kb + ((ch) * 128 + (idx >> 3)) * HDD + (idx & 7) * 8); \
      vreg[i] = *(const sh8*)(Vb + (idx >> 4) * SEQ + (ch) * 128 + (idx & 15) * 8); \
    } }
#define STAGE_WRITE(buf) { \
    _Pragma("unroll") \
    for (int i = 0; i < 4; ++i) { \
      int idx = i * 256 + tid; \
      *(sh8*)((char*)Kl[buf] + SWZA(idx >> 3, (idx & 7) * 16)) = kreg[i]; \
      *(sh8*)((char*)Vl[buf] + SWZB(idx >> 4, (idx & 15) * 16)) = vreg[i]; \
    } }

  STAGE_LOAD(0)
  STAGE_WRITE(0)
  __syncthreads();

  for (int ch = 0; ch < SEQ / 128; ++ch) {
    const int cur = ch & 1;
    if (ch < 7) STAGE_LOAD(ch + 1)      // issue early; lands under compute

    // S = Q K^T (Q pre-scaled to log2 units)
    f4 sacc[8];
#pragma unroll
    for (int n = 0; n < 8; ++n) sacc[n] = (f4){0.f, 0.f, 0.f, 0.f};
#pragma unroll
    for (int kk = 0; kk < 2; ++kk) {
#pragma unroll
      for (int n = 0; n < 8; ++n) {
        sh8 kf = *(const sh8*)((const char*)Kl[cur] + SWZA(n * 16 + lr, kk * 64 + lh * 16));
        sacc[n] = mfma16(qf[kk], kf, sacc[n]);
      }
    }

    // P = 2^S, partial row sums, P -> per-wave LDS (A-fragment layout)
#pragma unroll
    for (int n = 0; n < 8; ++n) {
#pragma unroll
      for (int r = 0; r < 4; ++r) {
        float pv = exp2f(sacc[n][r]);
        lsum[r] += pv;
        *(u16*)((char*)Pl[w] + SWZB(lh * 4 + r, (n * 16 + lr) * 2)) = f2bf(pv);
      }
    }

    // O += P V
#pragma unroll
    for (int kk = 0; kk < 4; ++kk) {
      sh8 pf = *(const sh8*)((const char*)Pl[w] + SWZB(lr, kk * 64 + lh * 16));
#pragma unroll
      for (int n = 0; n < 4; ++n) {
        sh8 vf = *(const sh8*)((const char*)Vl[cur] + SWZB(n * 16 + lr, kk * 64 + lh * 16));
        oacc[n] = mfma16(pf, vf, oacc[n]);
      }
    }

    if (ch < 7) STAGE_WRITE(cur ^ 1)    // other buffer; prior readers passed barrier(ch-1)
    __syncthreads();
  }
#undef STAGE_LOAD
#undef STAGE_WRITE

#pragma unroll
  for (int r = 0; r < 4; ++r) {
    lsum[r] += __shfl_xor(lsum[r], 1); lsum[r] += __shfl_xor(lsum[r], 2);
    lsum[r] += __shfl_xor(lsum[r], 4); lsum[r] += __shfl_xor(lsum[r], 8);
  }

  int bb = bh >> 3, h = bh & 7;
#pragma unroll
  for (int r = 0; r < 4; ++r) {
    int row = qt * 64 + w * 16 + lh * 4 + r;
    float inv = 1.f / lsum[r];
#pragma unroll
    for (int n = 0; n < 4; ++n)
      Ob[(bb * SEQ + row) * HD + h * 64 + n * 16 + lr] = f2bf(oacc[n][r] * inv);
  }
}

// ---------------- K3: out = a @ Wo^T + bo (MFMA, fp32 Wo converted in staging)
__global__ __launch_bounds__(256) void k_oproj_mfma(const u16* __restrict__ A,
    const float* __restrict__ W, const float* __restrict__ bo,
    float* __restrict__ out) {
  const int nb = blockIdx.x, ob = blockIdx.y;
  const int tid = threadIdx.x, w = tid >> 6, l = tid & 63;
  const int lr = l & 15, lh = l >> 4;
  __shared__ u16 Al[64 * 64];
  __shared__ u16 Wl[64 * 64];
  f4 acc[4];
#pragma unroll
  for (int n = 0; n < 4; ++n) acc[n] = (f4){0.f, 0.f, 0.f, 0.f};
  for (int ch = 0; ch < 8; ++ch) {
    __syncthreads();
#pragma unroll
    for (int i = 0; i < 2; ++i) {
      int idx = i * 256 + tid;
      int r = idx >> 3, c8 = idx & 7;
      *(sh8*)((char*)Al + SWZA(r, c8 * 16)) =
          *(const sh8*)(A + (nb * 64 + r) * HD + ch * 64 + c8 * 8);
      const float* wp = W + (ob * 64 + r) * HD + ch * 64 + c8 * 8;
      float4 f0 = *(const float4*)wp;
      float4 f1 = *(const float4*)(wp + 4);
      sh8 wv;
      wv[0] = (short)f2bf(f0.x); wv[1] = (short)f2bf(f0.y);
      wv[2] = (short)f2bf(f0.z); wv[3] = (short)f2bf(f0.w);
      wv[4] = (short)f2bf(f1.x); wv[5] = (short)f2bf(f1.y);
      wv[6] = (short)f2bf(f1.z); wv[7] = (short)f2bf(f1.w);
      *(sh8*)((char*)Wl + SWZA(r, c8 * 16)) = wv;
    }
    __syncthreads();
#pragma unroll
    for (int kk = 0; kk < 2; ++kk) {
      sh8 af = *(const sh8*)((const char*)Al + SWZA(w * 16 + lr, kk * 64 + lh * 16));
#pragma unroll
      for (int n = 0; n < 4; ++n) {
        sh8 wf = *(const sh8*)((const char*)Wl + SWZA(n * 16 + lr, kk * 64 + lh * 16));
        acc[n] = mfma16(af, wf, acc[n]);
      }
    }
  }
#pragma unroll
  for (int r = 0; r < 4; ++r) {
    int row = nb * 64 + w * 16 + lh * 4 + r;
#pragma unroll
    for (int n = 0; n < 4; ++n) {
      int col = ob * 64 + n * 16 + lr;
      out[row * HD + col] = acc[n][r] + bo[col];
    }
  }
}

// ---------------- launch ----------------
extern "C" void kernel_launch(void* const* d_in, const int* in_sizes, int n_in,
                              void* d_out, int out_size, void* d_ws, size_t ws_size,
                              hipStream_t stream) {
  const float* x    = (const float*)d_in[0];
  const float* Wp   = (const float*)d_in[1];
  const float* bp   = (const float*)d_in[2];
  const float* ln_g = (const float*)d_in[3];
  const float* ln_b = (const float*)d_in[4];
  const float* qw   = (const float*)d_in[5];
  const float* qe   = (const float*)d_in[6];
  const float* qg   = (const float*)d_in[7];
  const float* qb_  = (const float*)d_in[8];
  const float* kw   = (const float*)d_in[9];
  const float* ke   = (const float*)d_in[10];
  const float* kg   = (const float*)d_in[11];
  const float* kb_  = (const float*)d_in[12];
  const float* vw   = (const float*)d_in[13];
  const float* ve   = (const float*)d_in[14];
  const float* vg   = (const float*)d_in[15];
  const float* vb_  = (const float*)d_in[16];
  const float* Wq   = (const float*)d_in[17];
  const float* bq   = (const float*)d_in[18];
  const float* Wk   = (const float*)d_in[19];
  const float* bk   = (const float*)d_in[20];
  const float* Wv   = (const float*)d_in[21];
  const float* bv   = (const float*)d_in[22];
  const float* Wo   = (const float*)d_in[23];
  const float* bo   = (const float*)d_in[24];

  float* ws   = (float*)d_ws;
  float* Mbuf = ws;                        // 9216 f
  u16* qb  = (u16*)(Mbuf + 9216);          // 32*1024*64
  u16* kb  = qb + 32 * SEQ * HDD;
  u16* vtb = kb + 32 * SEQ * HDD;
  u16* ab  = vtb + 32 * SEQ * HDD;         // 4096*512

  k_prep<<<3, 256, 0, stream>>>(qw, qe, qg, qb_, kw, ke, kg, kb_,
                                vw, ve, vg, vb_, Mbuf);
  k_fused<<<NROWS / 16, 256, 0, stream>>>(x, Wp, bp, ln_g, ln_b, Mbuf,
                                          Wq, bq, Wk, bk, Wv, bv, qb, kb, vtb);
  dim3 ga(SEQ / 64, 32);
  k_attn_mfma<<<ga, 256, 0, stream>>>(qb, kb, vtb, ab);
  dim3 go(NROWS / 64, HD / 64);
  k_oproj_mfma<<<go, 256, 0, stream>>>(ab, Wo, bo, (float*)d_out);
}

// Round 7
// 84.802 us; speedup vs baseline: 1.3392x; 1.0191x over previous
//
#include <hip/hip_runtime.h>
#include <hip/hip_bf16.h>
#include <math.h>

#define NROWS 4096
#define HD 512
#define HEADS 8
#define HDD 64
#define SEQ 1024
#define QSCALE 0.18033688011112042f   // 0.125 * log2(e)

typedef unsigned short u16;
typedef unsigned int u32;
typedef __attribute__((ext_vector_type(8))) short sh8;   // 8 bf16 (4 VGPRs)
typedef __attribute__((ext_vector_type(4))) float f4;    // MFMA accumulator

__device__ __forceinline__ f4 mfma16(sh8 a, sh8 b, f4 c) {
  return __builtin_amdgcn_mfma_f32_16x16x32_bf16(a, b, c, 0, 0, 0);
}

__device__ __forceinline__ u16 f2bf(float x) {
  union { float f; unsigned u; } v; v.f = x;
  unsigned r = v.u + 0x7fff + ((v.u >> 16) & 1);   // RNE
  return (u16)(r >> 16);
}

// XOR swizzles: spread same-column ds_read_b128 across 8 distinct 16B slots.
#define SWZA(r, cb) ((((r) * 128) + (cb)) ^ (((r) & 7) << 4))   // 128B rows
#define SWZB(r, cb) ((((r) * 256) + (cb)) ^ (((r) & 7) << 4))   // 256B rows

// ---------------- K0: prep ----------------
// blocks 0..2: circuit -> U -> M[c][12][16][16] quadratic-form matrices
// blocks 3..5: convert Wq/Wk/Wv (+bias, +QSCALE for q) -> Wb[3][512][32] bf16
__global__ __launch_bounds__(256) void k_prep(
    const float* __restrict__ qw, const float* __restrict__ qe,
    const float* __restrict__ qg, const float* __restrict__ qb,
    const float* __restrict__ kw, const float* __restrict__ ke,
    const float* __restrict__ kg, const float* __restrict__ kb,
    const float* __restrict__ vw, const float* __restrict__ ve,
    const float* __restrict__ vg, const float* __restrict__ vb,
    const float* __restrict__ Wq, const float* __restrict__ bq,
    const float* __restrict__ Wk, const float* __restrict__ bk,
    const float* __restrict__ Wv, const float* __restrict__ bv,
    float* __restrict__ Mout, u16* __restrict__ Wbout) {
  const int c = blockIdx.x;
  const int tid = threadIdx.x;

  if (c >= 3) {    // ---- W conversion blocks ----
    const int c2 = c - 3;
    const float* W = (c2 == 0) ? Wq : (c2 == 1) ? Wk : Wv;
    const float* bb = (c2 == 0) ? bq : (c2 == 1) ? bk : bv;
    const float sc = (c2 == 0) ? QSCALE : 1.f;
    for (int o = tid; o < 512; o += 256) {
      unsigned out[16];
#pragma unroll
      for (int i = 0; i < 16; ++i) out[i] = 0u;
      const float* wr = W + o * 12;
#pragma unroll
      for (int jp = 0; jp < 6; ++jp)
        out[jp] = (unsigned)f2bf(wr[2*jp] * sc) | ((unsigned)f2bf(wr[2*jp+1] * sc) << 16);
      out[6] = (unsigned)f2bf(bb[o] * sc);      // bias in k-slot 12
      unsigned* dst = (unsigned*)(Wbout + (c2 * 512 + o) * 32);
#pragma unroll
      for (int i = 0; i < 16; ++i) dst[i] = out[i];
    }
    return;
  }

  __shared__ float aC[32], aS[32];
  __shared__ float GT[60][8];
  __shared__ int   GM[60][2];
  __shared__ float PF[3][16][2];
  __shared__ float SR[16][17], SI[16][17];
  __shared__ float TS[16], TI[16];
  __shared__ float Ur[256], Ui[256];

  const float* w = (c == 0) ? qw : (c == 1) ? kw : vw;
  const float* e = (c == 0) ? qe : (c == 1) ? ke : ve;
  const float* g = (c == 0) ? qg : (c == 1) ? kg : vg;
  const float* b = (c == 0) ? qb : (c == 1) ? kb : vb;

  if (tid < 30) {
    float ang = (tid < 12) ? w[tid] : (tid < 24) ? e[tid - 12]
               : (tid < 27) ? g[tid - 24] : b[tid - 27];
    float s_, c_;
    sincosf(0.5f * ang, &s_, &c_);
    aC[tid] = c_; aS[tid] = s_;
  }
  __syncthreads();

  if (tid < 60) {
    int L = tid / 20, s5 = tid % 20;
    int typ, aidx, M, C;
    if (s5 < 12) {
      int q = s5 / 3; typ = s5 % 3; aidx = L * 4 + q; M = 8 >> q; C = 0;
    } else if (s5 < 16) {
      int q = s5 - 12; typ = 0; aidx = 12 + L * 4 + q;
      C = 8 >> q; M = 8 >> ((q + 1) & 3);
    } else {
      int q = s5 - 16; typ = 0; aidx = 27 + L; M = 8 >> q; C = 0;
    }
    float cc = aC[aidx], ss = aS[aidx];
    float u0r = cc, u0i = 0.f, u1r = 0.f, u1i = 0.f,
          u2r = 0.f, u2i = 0.f, u3r = cc, u3i = 0.f;
    if (typ == 0)      { u1i = -ss; u2i = -ss; }
    else if (typ == 1) { u1r = -ss; u2r = ss; }
    else               { u0i = -ss; u3i = ss; }
    GT[tid][0] = u0r; GT[tid][1] = u0i; GT[tid][2] = u1r; GT[tid][3] = u1i;
    GT[tid][4] = u2r; GT[tid][5] = u2i; GT[tid][6] = u3r; GT[tid][7] = u3i;
    GM[tid][0] = M; GM[tid][1] = C;
  }
  if (tid >= 64 && tid < 112) {
    int idx = tid - 64, L = idx >> 4, a = idx & 15;
    float cg = aC[24 + L], sg = aS[24 + L];
    float c2 = cg * cg - sg * sg, s2 = 2.f * cg * sg;
    float c3 = cg * c2 - sg * s2, s3 = cg * s2 + sg * c2;
    int u = (a ^ (a >> 1)) & 7;
    int n = (u & 1) + ((u >> 1) & 1) + ((u >> 2) & 1);
    PF[L][a][0] = (n == 0 || n == 3) ? c3 : cg;
    PF[L][a][1] = (n == 0) ? -s3 : (n == 1) ? -sg : (n == 2) ? sg : s3;
  }
  for (int i = tid; i < 256; i += 256) {
    SR[i >> 4][i & 15] = (i >> 4) == (i & 15) ? 1.f : 0.f;
    SI[i >> 4][i & 15] = 0.f;
  }
  __syncthreads();

  const int p = tid >> 4, col = tid & 15;
  for (int L = 0; L < 3; ++L) {
    for (int s5 = 0; s5 < 16; ++s5) {
      if (tid < 128) {
        int gi = L * 20 + s5;
        const float* u = GT[gi];
        int M = GM[gi][0], C = GM[gi][1];
        int lo = p & (M - 1);
        int a = ((p - lo) << 1) | lo;
        int bb = a | M;
        bool act = (C == 0) | ((a & C) != 0);
        float ar = SR[a][col], ai = SI[a][col];
        float br = SR[bb][col], bi = SI[bb][col];
        float nar = u[0]*ar - u[1]*ai + u[2]*br - u[3]*bi;
        float nai = u[0]*ai + u[1]*ar + u[2]*bi + u[3]*br;
        float nbr = u[4]*ar - u[5]*ai + u[6]*br - u[7]*bi;
        float nbi = u[4]*ai + u[5]*ar + u[6]*bi + u[7]*br;
        SR[a][col]  = act ? nar : ar;  SI[a][col]  = act ? nai : ai;
        SR[bb][col] = act ? nbr : br;  SI[bb][col] = act ? nbi : bi;
      }
      __syncthreads();
    }
    if (tid < 16) {
      float sR = 0.f, sI = 0.f;
      for (int a = 0; a < 16; ++a) { sR += SR[a][tid]; sI += SI[a][tid]; }
      TS[tid] = sR * 0.125f; TI[tid] = sI * 0.125f;
    }
    __syncthreads();
    if (tid < 128) {
      for (int k = 0; k < 2; ++k) {
        int a = 2 * p + k;
        float vr = SR[a][col] - TS[col];
        float vi = SI[a][col] - TI[col];
        float pc = PF[L][a][0], ps = PF[L][a][1];
        SR[a][col] = vr * pc - vi * ps;
        SI[a][col] = vr * ps + vi * pc;
      }
    }
    __syncthreads();
    for (int s5 = 16; s5 < 20; ++s5) {
      if (tid < 128) {
        int gi = L * 20 + s5;
        const float* u = GT[gi];
        int M = GM[gi][0];
        int lo = p & (M - 1);
        int a = ((p - lo) << 1) | lo;
        int bb = a | M;
        float ar = SR[a][col], ai = SI[a][col];
        float br = SR[bb][col], bi = SI[bb][col];
        SR[a][col]  = u[0]*ar - u[1]*ai + u[2]*br - u[3]*bi;
        SI[a][col]  = u[0]*ai + u[1]*ar + u[2]*bi + u[3]*br;
        SR[bb][col] = u[4]*ar - u[5]*ai + u[6]*br - u[7]*bi;
        SI[bb][col] = u[4]*ai + u[5]*ar + u[6]*bi + u[7]*br;
      }
      __syncthreads();
    }
  }

  for (int i = tid; i < 256; i += 256) {
    Ur[i] = SR[i >> 4][i & 15];
    Ui[i] = SI[i >> 4][i & 15];
  }
  __syncthreads();

  if (tid < 192) {
    const int j = tid >> 4, a = tid & 15;
    const int typ = j >> 2;
    const int Mm = 8 >> (j & 3);
    float ax[4] = {0.f,0.f,0.f,0.f}, ay[4] = {0.f,0.f,0.f,0.f},
          az[4] = {0.f,0.f,0.f,0.f}, aw[4] = {0.f,0.f,0.f,0.f};
#pragma clang loop unroll_count(4)
    for (int k = 0; k < 16; ++k) {
      float uar = Ur[k * 16 + a], uai = Ui[k * 16 + a];
      int k2; float cR, cI;
      if (typ == 0)      { k2 = k;      float z = (k & Mm) ? -1.f : 1.f; cR = z*uar; cI = z*uai; }
      else if (typ == 1) { k2 = k ^ Mm; cR = uar; cI = uai; }
      else               { k2 = k ^ Mm; float sg = (k & Mm) ? 1.f : -1.f; cR = sg*uai; cI = -sg*uar; }
      const float* ur2 = Ur + k2 * 16;
      const float* ui2 = Ui + k2 * 16;
#pragma unroll
      for (int i = 0; i < 4; ++i) {
        ax[i] += cR * ur2[i*4+0] + cI * ui2[i*4+0];
        ay[i] += cR * ur2[i*4+1] + cI * ui2[i*4+1];
        az[i] += cR * ur2[i*4+2] + cI * ui2[i*4+2];
        aw[i] += cR * ur2[i*4+3] + cI * ui2[i*4+3];
      }
    }
    float* dst = Mout + ((c * 12 + j) * 16 + a) * 16;
#pragma unroll
    for (int i = 0; i < 4; ++i)
      ((float4*)dst)[i] = make_float4(ax[i], ay[i], az[i], aw[i]);
  }
}

// ---- K1 fused: x -> p -> psi -> t(bf16) -> MFMA QKV projection ----
// grid 256 blocks x 16 rows; Q,K [bh][s][64]; V transposed [bh][64][s]
__global__ __launch_bounds__(256) void k_fused(const float* __restrict__ x,
    const float* __restrict__ Wp, const float* __restrict__ bp,
    const float* __restrict__ ln_g, const float* __restrict__ ln_b,
    const float* __restrict__ Mg, const u16* __restrict__ Wb,
    u16* __restrict__ Qo, u16* __restrict__ Ko, u16* __restrict__ Vto) {
  const int rb = blockIdx.x;
  const int tid = threadIdx.x;
  __shared__ float Ml[3 * 12 * 256];   // 36 KB, j-XOR swizzled (float4 units)
  __shared__ float pl[16][4];
  __shared__ float psil[16][17];
  __shared__ u16 tb[3 * 16 * 32];      // bf16 A-tiles, K=32 padded; slot12 = 1.0

  { // stage M with XOR swizzle; init tb pads
    const float4* src = (const float4*)Mg;
    for (int f = tid; f < 2304; f += 256) {
      int cj = f >> 6, e4 = f & 63;
      int j = cj % 12;
      ((float4*)Ml)[cj * 64 + (e4 ^ (j & 7))] = src[f];
    }
    for (int i = tid; i < 768; i += 256) ((u32*)tb)[i] = 0u;
    if (tid < 48) tb[(tid >> 4) * 512 + (tid & 15) * 32 + 12] = 0x3F80;  // 1.0bf
  }

  // ---- phase A: p = LN(tanh(x @ Wp^T + bp)) for 16 rows ----
  const int w = tid >> 6, lane = tid & 63;
  {
    float4 wpa[4], wpb[4];
#pragma unroll
    for (int j = 0; j < 4; ++j) {
      wpa[j] = *(const float4*)(Wp + j * HD + lane * 8);
      wpb[j] = *(const float4*)(Wp + j * HD + lane * 8 + 4);
    }
    for (int i = 0; i < 4; ++i) {
      int r = w * 4 + i;
      const float* xr = x + (rb * 16 + r) * HD + lane * 8;
      float4 xa = *(const float4*)xr, xb = *(const float4*)(xr + 4);
      float acc[4];
#pragma unroll
      for (int j = 0; j < 4; ++j)
        acc[j] = xa.x*wpa[j].x + xa.y*wpa[j].y + xa.z*wpa[j].z + xa.w*wpa[j].w
               + xb.x*wpb[j].x + xb.y*wpb[j].y + xb.z*wpb[j].z + xb.w*wpb[j].w;
#pragma unroll
      for (int j = 0; j < 4; ++j)
#pragma unroll
        for (int off = 32; off >= 1; off >>= 1)
          acc[j] += __shfl_xor(acc[j], off);
      if (lane == 0) {
        float v0 = tanhf(acc[0] + bp[0]);
        float v1 = tanhf(acc[1] + bp[1]);
        float v2 = tanhf(acc[2] + bp[2]);
        float v3 = tanhf(acc[3] + bp[3]);
        float mu = 0.25f * (v0 + v1 + v2 + v3);
        float d0 = v0 - mu, d1 = v1 - mu, d2 = v2 - mu, d3 = v3 - mu;
        float inv = rsqrtf(0.25f * (d0*d0 + d1*d1 + d2*d2 + d3*d3) + 1e-5f);
        pl[r][0] = d0 * inv * ln_g[0] + ln_b[0];
        pl[r][1] = d1 * inv * ln_g[1] + ln_b[1];
        pl[r][2] = d2 * inv * ln_g[2] + ln_b[2];
        pl[r][3] = d3 * inv * ln_g[3] + ln_b[3];
      }
    }
  }
  __syncthreads();

  // ---- phase B1: psi per row ----
  if (tid < 16) {
    float cs[4], sn[4];
    sincosf(0.5f * pl[tid][0], &sn[0], &cs[0]);
    sincosf(0.5f * pl[tid][1], &sn[1], &cs[1]);
    sincosf(0.5f * pl[tid][2], &sn[2], &cs[2]);
    sincosf(0.5f * pl[tid][3], &sn[3], &cs[3]);
    float q01[4] = {cs[0]*cs[1], cs[0]*sn[1], sn[0]*cs[1], sn[0]*sn[1]};
    float q23[4] = {cs[2]*cs[3], cs[2]*sn[3], sn[2]*cs[3], sn[2]*sn[3]};
#pragma unroll
    for (int a = 0; a < 16; ++a) psil[tid][a] = q01[a >> 2] * q23[a & 3];
  }
  __syncthreads();

  // ---- phase B2: t[c][r][j] = psi^T M psi -> bf16 A-tile ----
  if (tid < 192) {
    const int r = tid & 15, j = tid >> 4;
    float psi[16];
#pragma unroll
    for (int a = 0; a < 16; ++a) psi[a] = psil[r][a];
#pragma clang loop unroll(disable)
    for (int c = 0; c < 3; ++c) {
      const float4* Mj = (const float4*)(Ml + (c * 12 + j) * 256);
      float y = 0.f;
#pragma unroll
      for (int a = 0; a < 16; ++a) {
        float rsum = 0.f;
#pragma unroll
        for (int i = 0; i < 4; ++i) {
          float4 m4 = Mj[(a * 4 + i) ^ (j & 7)];
          rsum += m4.x*psi[i*4] + m4.y*psi[i*4+1] + m4.z*psi[i*4+2] + m4.w*psi[i*4+3];
        }
        y += psi[a] * rsum;
      }
      tb[c * 512 + r * 32 + j] = f2bf(y);
    }
  }
  __syncthreads();

  // ---- phase C: QKV = tb @ Wb^T via MFMA (bias in k-slot 12) ----
  const int lr = lane & 15, lh = lane >> 4;
  const int b = rb >> 6, ss0 = (rb & 63) * 16;
  const f4 zero4 = (f4){0.f, 0.f, 0.f, 0.f};
#pragma unroll
  for (int c = 0; c < 3; ++c) {
    sh8 af = *(const sh8*)(tb + c * 512 + lr * 32 + lh * 8);
#pragma unroll
    for (int n = 0; n < 8; ++n) {
      int o = (w * 8 + n) * 16 + lr;
      sh8 bfr = *(const sh8*)(Wb + (c * 512 + o) * 32 + lh * 8);
      f4 acc = mfma16(af, bfr, zero4);
      if (c == 0) {
        int base = ((b * HEADS + (o >> 6)) * SEQ + ss0 + lh * 4) * HDD + (o & 63);
#pragma unroll
        for (int r = 0; r < 4; ++r) Qo[base + r * HDD] = f2bf(acc[r]);
      } else if (c == 1) {
        int base = ((b * HEADS + (o >> 6)) * SEQ + ss0 + lh * 4) * HDD + (o & 63);
#pragma unroll
        for (int r = 0; r < 4; ++r) Ko[base + r * HDD] = f2bf(acc[r]);
      } else {
        unsigned long long vv =
            (unsigned long long)((u32)f2bf(acc[0]) | ((u32)f2bf(acc[1]) << 16)) |
            ((unsigned long long)((u32)f2bf(acc[2]) | ((u32)f2bf(acc[3]) << 16)) << 32);
        *(unsigned long long*)(Vto + (b * 512 + o) * SEQ + ss0 + lh * 4) = vv;
      }
    }
  }
}

// ---------------- K2: MFMA flash attention, reg-staged double buffer ----------
__global__ __launch_bounds__(256) void k_attn_mfma(const u16* __restrict__ Q,
    const u16* __restrict__ K, const u16* __restrict__ Vt,
    u16* __restrict__ Ob) {
  const int bh = blockIdx.y, qt = blockIdx.x;
  const int tid = threadIdx.x, w = tid >> 6, l = tid & 63;
  const int lr = l & 15, lh = l >> 4;

  __shared__ u16 Kl[2][128 * 64];    // [key][d]  swizzled, 128B rows
  __shared__ u16 Vl[2][64 * 128];    // [d][key]  swizzled, 256B rows
  __shared__ u16 Pl[4][16 * 128];    // per-wave [q][key] swizzled

  const u16* Qb = Q + (bh * SEQ + qt * 64) * HDD;
  const u16* Kb = K + bh * SEQ * HDD;
  const u16* Vb = Vt + bh * HDD * SEQ;

  sh8 qf[2];
#pragma unroll
  for (int kk = 0; kk < 2; ++kk)
    qf[kk] = *(const sh8*)(Qb + (w * 16 + lr) * HDD + kk * 32 + lh * 8);

  f4 oacc[4];
  float lsum[4] = {0.f, 0.f, 0.f, 0.f};
#pragma unroll
  for (int n = 0; n < 4; ++n) oacc[n] = (f4){0.f, 0.f, 0.f, 0.f};

  sh8 kreg[4], vreg[4];

#define STAGE_LOAD(ch) { \
    _Pragma("unroll") \
    for (int i = 0; i < 4; ++i) { \
      int idx = i * 256 + tid; \
      kreg[i] = *(const sh8*)(Kb + ((ch) * 128 + (idx >> 3)) * HDD + (idx & 7) * 8); \
      vreg[i] = *(const sh8*)(Vb + (idx >> 4) * SEQ + (ch) * 128 + (idx & 15) * 8); \
    } }
#define STAGE_WRITE(buf) { \
    _Pragma("unroll") \
    for (int i = 0; i < 4; ++i) { \
      int idx = i * 256 + tid; \
      *(sh8*)((char*)Kl[buf] + SWZA(idx >> 3, (idx & 7) * 16)) = kreg[i]; \
      *(sh8*)((char*)Vl[buf] + SWZB(idx >> 4, (idx & 15) * 16)) = vreg[i]; \
    } }

  STAGE_LOAD(0)
  STAGE_WRITE(0)
  __syncthreads();

  for (int ch = 0; ch < SEQ / 128; ++ch) {
    const int cur = ch & 1;
    if (ch < 7) STAGE_LOAD(ch + 1)      // issue early; lands under compute

    f4 sacc[8];
#pragma unroll
    for (int n = 0; n < 8; ++n) sacc[n] = (f4){0.f, 0.f, 0.f, 0.f};
#pragma unroll
    for (int kk = 0; kk < 2; ++kk) {
#pragma unroll
      for (int n = 0; n < 8; ++n) {
        sh8 kf = *(const sh8*)((const char*)Kl[cur] + SWZA(n * 16 + lr, kk * 64 + lh * 16));
        sacc[n] = mfma16(qf[kk], kf, sacc[n]);
      }
    }

#pragma unroll
    for (int n = 0; n < 8; ++n) {
#pragma unroll
      for (int r = 0; r < 4; ++r) {
        float pv = exp2f(sacc[n][r]);
        lsum[r] += pv;
        *(u16*)((char*)Pl[w] + SWZB(lh * 4 + r, (n * 16 + lr) * 2)) = f2bf(pv);
      }
    }

#pragma unroll
    for (int kk = 0; kk < 4; ++kk) {
      sh8 pf = *(const sh8*)((const char*)Pl[w] + SWZB(lr, kk * 64 + lh * 16));
#pragma unroll
      for (int n = 0; n < 4; ++n) {
        sh8 vf = *(const sh8*)((const char*)Vl[cur] + SWZB(n * 16 + lr, kk * 64 + lh * 16));
        oacc[n] = mfma16(pf, vf, oacc[n]);
      }
    }

    if (ch < 7) STAGE_WRITE(cur ^ 1)
    __syncthreads();
  }
#undef STAGE_LOAD
#undef STAGE_WRITE

#pragma unroll
  for (int r = 0; r < 4; ++r) {
    lsum[r] += __shfl_xor(lsum[r], 1); lsum[r] += __shfl_xor(lsum[r], 2);
    lsum[r] += __shfl_xor(lsum[r], 4); lsum[r] += __shfl_xor(lsum[r], 8);
  }

  int bb = bh >> 3, h = bh & 7;
#pragma unroll
  for (int r = 0; r < 4; ++r) {
    int row = qt * 64 + w * 16 + lh * 4 + r;
    float inv = 1.f / lsum[r];
#pragma unroll
    for (int n = 0; n < 4; ++n)
      Ob[(bb * SEQ + row) * HD + h * 64 + n * 16 + lr] = f2bf(oacc[n][r] * inv);
  }
}

// ---------------- K3: out = a @ Wo^T + bo (MFMA, Wo converted in staging) ----
__global__ __launch_bounds__(256) void k_oproj_mfma(const u16* __restrict__ A,
    const float* __restrict__ W, const float* __restrict__ bo,
    float* __restrict__ out) {
  const int nb = blockIdx.x, ob = blockIdx.y;
  const int tid = threadIdx.x, w = tid >> 6, l = tid & 63;
  const int lr = l & 15, lh = l >> 4;
  __shared__ u16 Al[64 * 64];
  __shared__ u16 Wl[64 * 64];
  f4 acc[4];
#pragma unroll
  for (int n = 0; n < 4; ++n) acc[n] = (f4){0.f, 0.f, 0.f, 0.f};
  for (int ch = 0; ch < 8; ++ch) {
    __syncthreads();
#pragma unroll
    for (int i = 0; i < 2; ++i) {
      int idx = i * 256 + tid;
      int r = idx >> 3, c8 = idx & 7;
      *(sh8*)((char*)Al + SWZA(r, c8 * 16)) =
          *(const sh8*)(A + (nb * 64 + r) * HD + ch * 64 + c8 * 8);
      const float* wp = W + (ob * 64 + r) * HD + ch * 64 + c8 * 8;
      float4 f0 = *(const float4*)wp;
      float4 f1 = *(const float4*)(wp + 4);
      sh8 wv;
      wv[0] = (short)f2bf(f0.x); wv[1] = (short)f2bf(f0.y);
      wv[2] = (short)f2bf(f0.z); wv[3] = (short)f2bf(f0.w);
      wv[4] = (short)f2bf(f1.x); wv[5] = (short)f2bf(f1.y);
      wv[6] = (short)f2bf(f1.z); wv[7] = (short)f2bf(f1.w);
      *(sh8*)((char*)Wl + SWZA(r, c8 * 16)) = wv;
    }
    __syncthreads();
#pragma unroll
    for (int kk = 0; kk < 2; ++kk) {
      sh8 af = *(const sh8*)((const char*)Al + SWZA(w * 16 + lr, kk * 64 + lh * 16));
#pragma unroll
      for (int n = 0; n < 4; ++n) {
        sh8 wf = *(const sh8*)((const char*)Wl + SWZA(n * 16 + lr, kk * 64 + lh * 16));
        acc[n] = mfma16(af, wf, acc[n]);
      }
    }
  }
#pragma unroll
  for (int r = 0; r < 4; ++r) {
    int row = nb * 64 + w * 16 + lh * 4 + r;
#pragma unroll
    for (int n = 0; n < 4; ++n) {
      int col = ob * 64 + n * 16 + lr;
      out[row * HD + col] = acc[n][r] + bo[col];
    }
  }
}

// ---------------- launch ----------------
extern "C" void kernel_launch(void* const* d_in, const int* in_sizes, int n_in,
                              void* d_out, int out_size, void* d_ws, size_t ws_size,
                              hipStream_t stream) {
  const float* x    = (const float*)d_in[0];
  const float* Wp   = (const float*)d_in[1];
  const float* bp   = (const float*)d_in[2];
  const float* ln_g = (const float*)d_in[3];
  const float* ln_b = (const float*)d_in[4];
  const float* qw   = (const float*)d_in[5];
  const float* qe   = (const float*)d_in[6];
  const float* qg   = (const float*)d_in[7];
  const float* qb_  = (const float*)d_in[8];
  const float* kw   = (const float*)d_in[9];
  const float* ke   = (const float*)d_in[10];
  const float* kg   = (const float*)d_in[11];
  const float* kb_  = (const float*)d_in[12];
  const float* vw   = (const float*)d_in[13];
  const float* ve   = (const float*)d_in[14];
  const float* vg   = (const float*)d_in[15];
  const float* vb_  = (const float*)d_in[16];
  const float* Wq   = (const float*)d_in[17];
  const float* bq   = (const float*)d_in[18];
  const float* Wk   = (const float*)d_in[19];
  const float* bk   = (const float*)d_in[20];
  const float* Wv   = (const float*)d_in[21];
  const float* bv   = (const float*)d_in[22];
  const float* Wo   = (const float*)d_in[23];
  const float* bo   = (const float*)d_in[24];

  float* ws   = (float*)d_ws;
  float* Mbuf = ws;                        // 9216 f
  u16* Wbb = (u16*)(Mbuf + 9216);          // 3*512*32 = 49152 u16
  u16* qb  = Wbb + 49152;                  // 32*1024*64
  u16* kb  = qb + 32 * SEQ * HDD;
  u16* vtb = kb + 32 * SEQ * HDD;
  u16* ab  = vtb + 32 * SEQ * HDD;         // 4096*512

  k_prep<<<6, 256, 0, stream>>>(qw, qe, qg, qb_, kw, ke, kg, kb_,
                                vw, ve, vg, vb_, Wq, bq, Wk, bk, Wv, bv,
                                Mbuf, Wbb);
  k_fused<<<NROWS / 16, 256, 0, stream>>>(x, Wp, bp, ln_g, ln_b, Mbuf, Wbb,
                                          qb, kb, vtb);
  dim3 ga(SEQ / 64, 32);
  k_attn_mfma<<<ga, 256, 0, stream>>>(qb, kb, vtb, ab);
  dim3 go(NROWS / 64, HD / 64);
  k_oproj_mfma<<<go, 256, 0, stream>>>(ab, Wo, bo, (float*)d_out);
}

// Round 8
// 80.545 us; speedup vs baseline: 1.4100x; 1.0529x over previous
//
#include <hip/hip_runtime.h>
#include <hip/hip_bf16.h>
#include <math.h>

#define NROWS 4096
#define HD 512
#define HEADS 8
#define HDD 64
#define SEQ 1024
#define QSCALE 0.18033688011112042f   // 0.125 * log2(e)

typedef unsigned short u16;
typedef unsigned int u32;
typedef __attribute__((ext_vector_type(8))) short sh8;   // 8 bf16 (4 VGPRs)
typedef __attribute__((ext_vector_type(4))) float f4;    // MFMA accumulator

__device__ __forceinline__ f4 mfma16(sh8 a, sh8 b, f4 c) {
  return __builtin_amdgcn_mfma_f32_16x16x32_bf16(a, b, c, 0, 0, 0);
}

__device__ __forceinline__ u16 f2bf(float x) {
  union { float f; unsigned u; } v; v.f = x;
  unsigned r = v.u + 0x7fff + ((v.u >> 16) & 1);   // RNE
  return (u16)(r >> 16);
}

// XOR swizzles: spread same-column ds_read_b128 across 8 distinct 16B slots.
#define SWZA(r, cb) ((((r) * 128) + (cb)) ^ (((r) & 7) << 4))   // 128B rows
#define SWZB(r, cb) ((((r) * 256) + (cb)) ^ (((r) & 7) << 4))   // 256B rows

// ---------------- K0: prep ----------------
// blocks 0..2: circuit -> U -> M[c][12][16][16] quadratic-form matrices
// blocks 3..5: convert Wq/Wk/Wv (+bias, +QSCALE for q) -> Wb[3][512][32] bf16
__global__ __launch_bounds__(256) void k_prep(
    const float* __restrict__ qw, const float* __restrict__ qe,
    const float* __restrict__ qg, const float* __restrict__ qb,
    const float* __restrict__ kw, const float* __restrict__ ke,
    const float* __restrict__ kg, const float* __restrict__ kb,
    const float* __restrict__ vw, const float* __restrict__ ve,
    const float* __restrict__ vg, const float* __restrict__ vb,
    const float* __restrict__ Wq, const float* __restrict__ bq,
    const float* __restrict__ Wk, const float* __restrict__ bk,
    const float* __restrict__ Wv, const float* __restrict__ bv,
    float* __restrict__ Mout, u16* __restrict__ Wbout) {
  const int c = blockIdx.x;
  const int tid = threadIdx.x;

  if (c >= 3) {    // ---- W conversion blocks ----
    const int c2 = c - 3;
    const float* W = (c2 == 0) ? Wq : (c2 == 1) ? Wk : Wv;
    const float* bb = (c2 == 0) ? bq : (c2 == 1) ? bk : bv;
    const float sc = (c2 == 0) ? QSCALE : 1.f;
    for (int o = tid; o < 512; o += 256) {
      unsigned out[16];
#pragma unroll
      for (int i = 0; i < 16; ++i) out[i] = 0u;
      const float* wr = W + o * 12;
#pragma unroll
      for (int jp = 0; jp < 6; ++jp)
        out[jp] = (unsigned)f2bf(wr[2*jp] * sc) | ((unsigned)f2bf(wr[2*jp+1] * sc) << 16);
      out[6] = (unsigned)f2bf(bb[o] * sc);      // bias in k-slot 12
      unsigned* dst = (unsigned*)(Wbout + (c2 * 512 + o) * 32);
#pragma unroll
      for (int i = 0; i < 16; ++i) dst[i] = out[i];
    }
    return;
  }

  __shared__ float aC[32], aS[32];
  __shared__ float GT[60][8];
  __shared__ int   GM[60][2];
  __shared__ float PF[3][16][2];
  __shared__ float SR[16][17], SI[16][17];
  __shared__ float TS[16], TI[16];
  __shared__ float Ur[256], Ui[256];

  const float* w = (c == 0) ? qw : (c == 1) ? kw : vw;
  const float* e = (c == 0) ? qe : (c == 1) ? ke : ve;
  const float* g = (c == 0) ? qg : (c == 1) ? kg : vg;
  const float* b = (c == 0) ? qb : (c == 1) ? kb : vb;

  if (tid < 30) {
    float ang = (tid < 12) ? w[tid] : (tid < 24) ? e[tid - 12]
               : (tid < 27) ? g[tid - 24] : b[tid - 27];
    float s_, c_;
    sincosf(0.5f * ang, &s_, &c_);
    aC[tid] = c_; aS[tid] = s_;
  }
  __syncthreads();

  if (tid < 60) {
    int L = tid / 20, s5 = tid % 20;
    int typ, aidx, M, C;
    if (s5 < 12) {
      int q = s5 / 3; typ = s5 % 3; aidx = L * 4 + q; M = 8 >> q; C = 0;
    } else if (s5 < 16) {
      int q = s5 - 12; typ = 0; aidx = 12 + L * 4 + q;
      C = 8 >> q; M = 8 >> ((q + 1) & 3);
    } else {
      int q = s5 - 16; typ = 0; aidx = 27 + L; M = 8 >> q; C = 0;
    }
    float cc = aC[aidx], ss = aS[aidx];
    float u0r = cc, u0i = 0.f, u1r = 0.f, u1i = 0.f,
          u2r = 0.f, u2i = 0.f, u3r = cc, u3i = 0.f;
    if (typ == 0)      { u1i = -ss; u2i = -ss; }
    else if (typ == 1) { u1r = -ss; u2r = ss; }
    else               { u0i = -ss; u3i = ss; }
    GT[tid][0] = u0r; GT[tid][1] = u0i; GT[tid][2] = u1r; GT[tid][3] = u1i;
    GT[tid][4] = u2r; GT[tid][5] = u2i; GT[tid][6] = u3r; GT[tid][7] = u3i;
    GM[tid][0] = M; GM[tid][1] = C;
  }
  if (tid >= 64 && tid < 112) {
    int idx = tid - 64, L = idx >> 4, a = idx & 15;
    float cg = aC[24 + L], sg = aS[24 + L];
    float c2 = cg * cg - sg * sg, s2 = 2.f * cg * sg;
    float c3 = cg * c2 - sg * s2, s3 = cg * s2 + sg * c2;
    int u = (a ^ (a >> 1)) & 7;
    int n = (u & 1) + ((u >> 1) & 1) + ((u >> 2) & 1);
    PF[L][a][0] = (n == 0 || n == 3) ? c3 : cg;
    PF[L][a][1] = (n == 0) ? -s3 : (n == 1) ? -sg : (n == 2) ? sg : s3;
  }
  for (int i = tid; i < 256; i += 256) {
    SR[i >> 4][i & 15] = (i >> 4) == (i & 15) ? 1.f : 0.f;
    SI[i >> 4][i & 15] = 0.f;
  }
  __syncthreads();

  const int p = tid >> 4, col = tid & 15;
  for (int L = 0; L < 3; ++L) {
    for (int s5 = 0; s5 < 16; ++s5) {
      if (tid < 128) {
        int gi = L * 20 + s5;
        const float* u = GT[gi];
        int M = GM[gi][0], C = GM[gi][1];
        int lo = p & (M - 1);
        int a = ((p - lo) << 1) | lo;
        int bb = a | M;
        bool act = (C == 0) | ((a & C) != 0);
        float ar = SR[a][col], ai = SI[a][col];
        float br = SR[bb][col], bi = SI[bb][col];
        float nar = u[0]*ar - u[1]*ai + u[2]*br - u[3]*bi;
        float nai = u[0]*ai + u[1]*ar + u[2]*bi + u[3]*br;
        float nbr = u[4]*ar - u[5]*ai + u[6]*br - u[7]*bi;
        float nbi = u[4]*ai + u[5]*ar + u[6]*bi + u[7]*br;
        SR[a][col]  = act ? nar : ar;  SI[a][col]  = act ? nai : ai;
        SR[bb][col] = act ? nbr : br;  SI[bb][col] = act ? nbi : bi;
      }
      __syncthreads();
    }
    if (tid < 16) {
      float sR = 0.f, sI = 0.f;
      for (int a = 0; a < 16; ++a) { sR += SR[a][tid]; sI += SI[a][tid]; }
      TS[tid] = sR * 0.125f; TI[tid] = sI * 0.125f;
    }
    __syncthreads();
    if (tid < 128) {
      for (int k = 0; k < 2; ++k) {
        int a = 2 * p + k;
        float vr = SR[a][col] - TS[col];
        float vi = SI[a][col] - TI[col];
        float pc = PF[L][a][0], ps = PF[L][a][1];
        SR[a][col] = vr * pc - vi * ps;
        SI[a][col] = vr * ps + vi * pc;
      }
    }
    __syncthreads();
    for (int s5 = 16; s5 < 20; ++s5) {
      if (tid < 128) {
        int gi = L * 20 + s5;
        const float* u = GT[gi];
        int M = GM[gi][0];
        int lo = p & (M - 1);
        int a = ((p - lo) << 1) | lo;
        int bb = a | M;
        float ar = SR[a][col], ai = SI[a][col];
        float br = SR[bb][col], bi = SI[bb][col];
        SR[a][col]  = u[0]*ar - u[1]*ai + u[2]*br - u[3]*bi;
        SI[a][col]  = u[0]*ai + u[1]*ar + u[2]*bi + u[3]*br;
        SR[bb][col] = u[4]*ar - u[5]*ai + u[6]*br - u[7]*bi;
        SI[bb][col] = u[4]*ai + u[5]*ar + u[6]*bi + u[7]*br;
      }
      __syncthreads();
    }
  }

  for (int i = tid; i < 256; i += 256) {
    Ur[i] = SR[i >> 4][i & 15];
    Ui[i] = SI[i >> 4][i & 15];
  }
  __syncthreads();

  if (tid < 192) {
    const int j = tid >> 4, a = tid & 15;
    const int typ = j >> 2;
    const int Mm = 8 >> (j & 3);
    float ax[4] = {0.f,0.f,0.f,0.f}, ay[4] = {0.f,0.f,0.f,0.f},
          az[4] = {0.f,0.f,0.f,0.f}, aw[4] = {0.f,0.f,0.f,0.f};
#pragma clang loop unroll_count(4)
    for (int k = 0; k < 16; ++k) {
      float uar = Ur[k * 16 + a], uai = Ui[k * 16 + a];
      int k2; float cR, cI;
      if (typ == 0)      { k2 = k;      float z = (k & Mm) ? -1.f : 1.f; cR = z*uar; cI = z*uai; }
      else if (typ == 1) { k2 = k ^ Mm; cR = uar; cI = uai; }
      else               { k2 = k ^ Mm; float sg = (k & Mm) ? 1.f : -1.f; cR = sg*uai; cI = -sg*uar; }
      const float* ur2 = Ur + k2 * 16;
      const float* ui2 = Ui + k2 * 16;
#pragma unroll
      for (int i = 0; i < 4; ++i) {
        ax[i] += cR * ur2[i*4+0] + cI * ui2[i*4+0];
        ay[i] += cR * ur2[i*4+1] + cI * ui2[i*4+1];
        az[i] += cR * ur2[i*4+2] + cI * ui2[i*4+2];
        aw[i] += cR * ur2[i*4+3] + cI * ui2[i*4+3];
      }
    }
    float* dst = Mout + ((c * 12 + j) * 16 + a) * 16;
#pragma unroll
    for (int i = 0; i < 4; ++i)
      ((float4*)dst)[i] = make_float4(ax[i], ay[i], az[i], aw[i]);
  }
}

// ---------------- K1: p = LN(tanh(x @ Wp^T + bp)) ----------------
__global__ __launch_bounds__(256) void k_ln(const float* __restrict__ x,
    const float* __restrict__ Wp, const float* __restrict__ bp,
    const float* __restrict__ g, const float* __restrict__ b,
    float* __restrict__ p) {
  int row  = blockIdx.x * 4 + (threadIdx.x >> 6);
  int lane = threadIdx.x & 63;
  const float* xr = x + row * HD + lane * 8;
  float4 xa = *(const float4*)xr;
  float4 xb = *(const float4*)(xr + 4);
  float acc[4];
#pragma unroll
  for (int j = 0; j < 4; ++j) {
    const float* wr = Wp + j * HD + lane * 8;
    float4 wa = *(const float4*)wr;
    float4 wb = *(const float4*)(wr + 4);
    acc[j] = xa.x*wa.x + xa.y*wa.y + xa.z*wa.z + xa.w*wa.w
           + xb.x*wb.x + xb.y*wb.y + xb.z*wb.z + xb.w*wb.w;
  }
#pragma unroll
  for (int j = 0; j < 4; ++j) {
#pragma unroll
    for (int off = 32; off >= 1; off >>= 1)
      acc[j] += __shfl_xor(acc[j], off);
  }
  if (lane == 0) {
    float v0 = tanhf(acc[0] + bp[0]);
    float v1 = tanhf(acc[1] + bp[1]);
    float v2 = tanhf(acc[2] + bp[2]);
    float v3 = tanhf(acc[3] + bp[3]);
    float mu = 0.25f * (v0 + v1 + v2 + v3);
    float d0 = v0 - mu, d1 = v1 - mu, d2 = v2 - mu, d3 = v3 - mu;
    float inv = rsqrtf(0.25f * (d0*d0 + d1*d1 + d2*d2 + d3*d3) + 1e-5f);
    *(float4*)(p + row * 4) = make_float4(d0*inv*g[0] + b[0], d1*inv*g[1] + b[1],
                                          d2*inv*g[2] + b[2], d3*inv*g[3] + b[3]);
  }
}

// ---- K2: per (rowblock, circuit): p -> psi -> t(bf16) -> MFMA projection ----
// grid (256, 3); Q,K [bh][s][64]; V transposed [bh][64][s]
__global__ __launch_bounds__(256) void k_qkv(const float* __restrict__ p,
    const float* __restrict__ Mg, const u16* __restrict__ Wb,
    u16* __restrict__ Qo, u16* __restrict__ Ko, u16* __restrict__ Vto) {
  const int rb = blockIdx.x, c = blockIdx.y;
  const int tid = threadIdx.x;
  __shared__ float psil[16][17];
  __shared__ u16 tb[16 * 32];          // bf16 A-tile, K=32 padded; slot12 = 1.0

  // init tb pads (u32 i covers slots 2i,2i+1 of row i>>4)
  ((u32*)tb)[tid] = ((tid & 15) == 6) ? 0x3F80u : 0u;

  // psi per row
  if (tid < 16) {
    float4 in4 = *(const float4*)(p + (rb * 16 + tid) * 4);
    float cs[4], sn[4];
    sincosf(0.5f * in4.x, &sn[0], &cs[0]);
    sincosf(0.5f * in4.y, &sn[1], &cs[1]);
    sincosf(0.5f * in4.z, &sn[2], &cs[2]);
    sincosf(0.5f * in4.w, &sn[3], &cs[3]);
    float q01[4] = {cs[0]*cs[1], cs[0]*sn[1], sn[0]*cs[1], sn[0]*sn[1]};
    float q23[4] = {cs[2]*cs[3], cs[2]*sn[3], sn[2]*cs[3], sn[2]*sn[3]};
#pragma unroll
    for (int a = 0; a < 16; ++a) psil[tid][a] = q01[a >> 2] * q23[a & 3];
  }
  __syncthreads();

  // t[r][j] = psi^T M[c][j] psi  (M direct from L2; same-j lanes broadcast)
  if (tid < 192) {
    const int r = tid & 15, j = tid >> 4;
    float psi[16];
#pragma unroll
    for (int a = 0; a < 16; ++a) psi[a] = psil[r][a];
    const float4* Mj = (const float4*)(Mg + (c * 12 + j) * 256);
    float y = 0.f;
#pragma unroll
    for (int a = 0; a < 16; ++a) {
      float rsum = 0.f;
#pragma unroll
      for (int i = 0; i < 4; ++i) {
        float4 m4 = Mj[a * 4 + i];
        rsum += m4.x*psi[i*4] + m4.y*psi[i*4+1] + m4.z*psi[i*4+2] + m4.w*psi[i*4+3];
      }
      y += psi[a] * rsum;
    }
    tb[r * 32 + j] = f2bf(y);
  }
  __syncthreads();

  // QKV = tb @ Wb[c]^T via MFMA (bias in k-slot 12)
  const int w = tid >> 6, lane = tid & 63;
  const int lr = lane & 15, lh = lane >> 4;
  const int b = rb >> 6, ss0 = (rb & 63) * 16;
  const f4 zero4 = (f4){0.f, 0.f, 0.f, 0.f};
  sh8 af = *(const sh8*)(tb + lr * 32 + lh * 8);
#pragma unroll
  for (int n = 0; n < 8; ++n) {
    int o = (w * 8 + n) * 16 + lr;
    sh8 bfr = *(const sh8*)(Wb + (c * 512 + o) * 32 + lh * 8);
    f4 acc = mfma16(af, bfr, zero4);
    if (c == 0) {
      int base = ((b * HEADS + (o >> 6)) * SEQ + ss0 + lh * 4) * HDD + (o & 63);
#pragma unroll
      for (int r = 0; r < 4; ++r) Qo[base + r * HDD] = f2bf(acc[r]);
    } else if (c == 1) {
      int base = ((b * HEADS + (o >> 6)) * SEQ + ss0 + lh * 4) * HDD + (o & 63);
#pragma unroll
      for (int r = 0; r < 4; ++r) Ko[base + r * HDD] = f2bf(acc[r]);
    } else {
      unsigned long long vv =
          (unsigned long long)((u32)f2bf(acc[0]) | ((u32)f2bf(acc[1]) << 16)) |
          ((unsigned long long)((u32)f2bf(acc[2]) | ((u32)f2bf(acc[3]) << 16)) << 32);
      *(unsigned long long*)(Vto + (b * 512 + o) * SEQ + ss0 + lh * 4) = vv;
    }
  }
}

// ---------------- K3: MFMA flash attention, reg-staged double buffer ----------
__global__ __launch_bounds__(256) void k_attn_mfma(const u16* __restrict__ Q,
    const u16* __restrict__ K, const u16* __restrict__ Vt,
    u16* __restrict__ Ob) {
  const int bh = blockIdx.y, qt = blockIdx.x;
  const int tid = threadIdx.x, w = tid >> 6, l = tid & 63;
  const int lr = l & 15, lh = l >> 4;

  __shared__ u16 Kl[2][128 * 64];    // [key][d]  swizzled, 128B rows
  __shared__ u16 Vl[2][64 * 128];    // [d][key]  swizzled, 256B rows
  __shared__ u16 Pl[4][16 * 128];    // per-wave [q][key] swizzled

  const u16* Qb = Q + (bh * SEQ + qt * 64) * HDD;
  const u16* Kb = K + bh * SEQ * HDD;
  const u16* Vb = Vt + bh * HDD * SEQ;

  sh8 qf[2];
#pragma unroll
  for (int kk = 0; kk < 2; ++kk)
    qf[kk] = *(const sh8*)(Qb + (w * 16 + lr) * HDD + kk * 32 + lh * 8);

  f4 oacc[4];
  float lsum[4] = {0.f, 0.f, 0.f, 0.f};
#pragma unroll
  for (int n = 0; n < 4; ++n) oacc[n] = (f4){0.f, 0.f, 0.f, 0.f};

  sh8 kreg[4], vreg[4];

#define STAGE_LOAD(ch) { \
    _Pragma("unroll") \
    for (int i = 0; i < 4; ++i) { \
      int idx = i * 256 + tid; \
      kreg[i] = *(const sh8*)(Kb + ((ch) * 128 + (idx >> 3)) * HDD + (idx & 7) * 8); \
      vreg[i] = *(const sh8*)(Vb + (idx >> 4) * SEQ + (ch) * 128 + (idx & 15) * 8); \
    } }
#define STAGE_WRITE(buf) { \
    _Pragma("unroll") \
    for (int i = 0; i < 4; ++i) { \
      int idx = i * 256 + tid; \
      *(sh8*)((char*)Kl[buf] + SWZA(idx >> 3, (idx & 7) * 16)) = kreg[i]; \
      *(sh8*)((char*)Vl[buf] + SWZB(idx >> 4, (idx & 15) * 16)) = vreg[i]; \
    } }

  STAGE_LOAD(0)
  STAGE_WRITE(0)
  __syncthreads();

  for (int ch = 0; ch < SEQ / 128; ++ch) {
    const int cur = ch & 1;
    if (ch < 7) STAGE_LOAD(ch + 1)      // issue early; lands under compute

    f4 sacc[8];
#pragma unroll
    for (int n = 0; n < 8; ++n) sacc[n] = (f4){0.f, 0.f, 0.f, 0.f};
#pragma unroll
    for (int kk = 0; kk < 2; ++kk) {
#pragma unroll
      for (int n = 0; n < 8; ++n) {
        sh8 kf = *(const sh8*)((const char*)Kl[cur] + SWZA(n * 16 + lr, kk * 64 + lh * 16));
        sacc[n] = mfma16(qf[kk], kf, sacc[n]);
      }
    }

#pragma unroll
    for (int n = 0; n < 8; ++n) {
#pragma unroll
      for (int r = 0; r < 4; ++r) {
        float pv = exp2f(sacc[n][r]);
        lsum[r] += pv;
        *(u16*)((char*)Pl[w] + SWZB(lh * 4 + r, (n * 16 + lr) * 2)) = f2bf(pv);
      }
    }

#pragma unroll
    for (int kk = 0; kk < 4; ++kk) {
      sh8 pf = *(const sh8*)((const char*)Pl[w] + SWZB(lr, kk * 64 + lh * 16));
#pragma unroll
      for (int n = 0; n < 4; ++n) {
        sh8 vf = *(const sh8*)((const char*)Vl[cur] + SWZB(n * 16 + lr, kk * 64 + lh * 16));
        oacc[n] = mfma16(pf, vf, oacc[n]);
      }
    }

    if (ch < 7) STAGE_WRITE(cur ^ 1)
    __syncthreads();
  }
#undef STAGE_LOAD
#undef STAGE_WRITE

#pragma unroll
  for (int r = 0; r < 4; ++r) {
    lsum[r] += __shfl_xor(lsum[r], 1); lsum[r] += __shfl_xor(lsum[r], 2);
    lsum[r] += __shfl_xor(lsum[r], 4); lsum[r] += __shfl_xor(lsum[r], 8);
  }

  int bb = bh >> 3, h = bh & 7;
#pragma unroll
  for (int r = 0; r < 4; ++r) {
    int row = qt * 64 + w * 16 + lh * 4 + r;
    float inv = 1.f / lsum[r];
#pragma unroll
    for (int n = 0; n < 4; ++n)
      Ob[(bb * SEQ + row) * HD + h * 64 + n * 16 + lr] = f2bf(oacc[n][r] * inv);
  }
}

// ---------------- K4: out = a @ Wo^T + bo (MFMA, Wo converted in staging) ----
__global__ __launch_bounds__(256) void k_oproj_mfma(const u16* __restrict__ A,
    const float* __restrict__ W, const float* __restrict__ bo,
    float* __restrict__ out) {
  const int nb = blockIdx.x, ob = blockIdx.y;
  const int tid = threadIdx.x, w = tid >> 6, l = tid & 63;
  const int lr = l & 15, lh = l >> 4;
  __shared__ u16 Al[64 * 64];
  __shared__ u16 Wl[64 * 64];
  f4 acc[4];
#pragma unroll
  for (int n = 0; n < 4; ++n) acc[n] = (f4){0.f, 0.f, 0.f, 0.f};
  for (int ch = 0; ch < 8; ++ch) {
    __syncthreads();
#pragma unroll
    for (int i = 0; i < 2; ++i) {
      int idx = i * 256 + tid;
      int r = idx >> 3, c8 = idx & 7;
      *(sh8*)((char*)Al + SWZA(r, c8 * 16)) =
          *(const sh8*)(A + (nb * 64 + r) * HD + ch * 64 + c8 * 8);
      const float* wp = W + (ob * 64 + r) * HD + ch * 64 + c8 * 8;
      float4 f0 = *(const float4*)wp;
      float4 f1 = *(const float4*)(wp + 4);
      sh8 wv;
      wv[0] = (short)f2bf(f0.x); wv[1] = (short)f2bf(f0.y);
      wv[2] = (short)f2bf(f0.z); wv[3] = (short)f2bf(f0.w);
      wv[4] = (short)f2bf(f1.x); wv[5] = (short)f2bf(f1.y);
      wv[6] = (short)f2bf(f1.z); wv[7] = (short)f2bf(f1.w);
      *(sh8*)((char*)Wl + SWZA(r, c8 * 16)) = wv;
    }
    __syncthreads();
#pragma unroll
    for (int kk = 0; kk < 2; ++kk) {
      sh8 af = *(const sh8*)((const char*)Al + SWZA(w * 16 + lr, kk * 64 + lh * 16));
#pragma unroll
      for (int n = 0; n < 4; ++n) {
        sh8 wf = *(const sh8*)((const char*)Wl + SWZA(n * 16 + lr, kk * 64 + lh * 16));
        acc[n] = mfma16(af, wf, acc[n]);
      }
    }
  }
#pragma unroll
  for (int r = 0; r < 4; ++r) {
    int row = nb * 64 + w * 16 + lh * 4 + r;
#pragma unroll
    for (int n = 0; n < 4; ++n) {
      int col = ob * 64 + n * 16 + lr;
      out[row * HD + col] = acc[n][r] + bo[col];
    }
  }
}

// ---------------- launch ----------------
extern "C" void kernel_launch(void* const* d_in, const int* in_sizes, int n_in,
                              void* d_out, int out_size, void* d_ws, size_t ws_size,
                              hipStream_t stream) {
  const float* x    = (const float*)d_in[0];
  const float* Wp   = (const float*)d_in[1];
  const float* bp   = (const float*)d_in[2];
  const float* ln_g = (const float*)d_in[3];
  const float* ln_b = (const float*)d_in[4];
  const float* qw   = (const float*)d_in[5];
  const float* qe   = (const float*)d_in[6];
  const float* qg   = (const float*)d_in[7];
  const float* qb_  = (const float*)d_in[8];
  const float* kw   = (const float*)d_in[9];
  const float* ke   = (const float*)d_in[10];
  const float* kg   = (const float*)d_in[11];
  const float* kb_  = (const float*)d_in[12];
  const float* vw   = (const float*)d_in[13];
  const float* ve   = (const float*)d_in[14];
  const float* vg   = (const float*)d_in[15];
  const float* vb_  = (const float*)d_in[16];
  const float* Wq   = (const float*)d_in[17];
  const float* bq   = (const float*)d_in[18];
  const float* Wk   = (const float*)d_in[19];
  const float* bk   = (const float*)d_in[20];
  const float* Wv   = (const float*)d_in[21];
  const float* bv   = (const float*)d_in[22];
  const float* Wo   = (const float*)d_in[23];
  const float* bo   = (const float*)d_in[24];

  float* ws   = (float*)d_ws;
  float* Mbuf = ws;                        // 9216 f
  float* pbuf = Mbuf + 9216;               // 16384 f
  u16* Wbb = (u16*)(pbuf + 16384);         // 3*512*32 = 49152 u16
  u16* qb  = Wbb + 49152;                  // 32*1024*64
  u16* kb  = qb + 32 * SEQ * HDD;
  u16* vtb = kb + 32 * SEQ * HDD;
  u16* ab  = vtb + 32 * SEQ * HDD;         // 4096*512

  k_prep<<<6, 256, 0, stream>>>(qw, qe, qg, qb_, kw, ke, kg, kb_,
                                vw, ve, vg, vb_, Wq, bq, Wk, bk, Wv, bv,
                                Mbuf, Wbb);
  k_ln<<<NROWS / 4, 256, 0, stream>>>(x, Wp, bp, ln_g, ln_b, pbuf);
  dim3 gq(NROWS / 16, 3);
  k_qkv<<<gq, 256, 0, stream>>>(pbuf, Mbuf, Wbb, qb, kb, vtb);
  dim3 ga(SEQ / 64, 32);
  k_attn_mfma<<<ga, 256, 0, stream>>>(qb, kb, vtb, ab);
  dim3 go(NROWS / 64, HD / 64);
  k_oproj_mfma<<<go, 256, 0, stream>>>(ab, Wo, bo, (float*)d_out);
}